// Round 1
// baseline (3933.430 us; speedup 1.0000x reference)
//
#include <hip/hip_runtime.h>
#include <math.h>

// dims
// B=8, DM=256, H=W=32, L=HW=1024, R=4, DI=512, DH=256, N=16, K=4, DTR=16

__device__ __forceinline__ int srcmap(int r, int l) {
  // rotated position l=(i,j) -> original pixel index h*32+w
  int i = l >> 5, j = l & 31;
  int h, w;
  if (r == 0)      { h = i;      w = j;      }
  else if (r == 1) { h = j;      w = 31 - i; }
  else if (r == 2) { h = 31 - i; w = 31 - j; }
  else             { h = 31 - j; w = i;      }
  return (h << 5) + w;
}

__device__ __forceinline__ float siluf(float x)    { return x / (1.f + __expf(-x)); }
__device__ __forceinline__ float sigmoidf_(float x){ return 1.f / (1.f + __expf(-x)); }
__device__ __forceinline__ float geluf(float x) {
  float x3 = x * x * x;
  return 0.5f * x * (1.f + tanhf(0.7978845608028654f * (x + 0.044715f * x3)));
}

// ---------------- weight pre-transposes ----------------
// inWT[c*512+d]  = in_proj_w[d*256+c]
// opWT[d*256+co] = out_proj_w[co*512+d]
// gwT[d*512+c]   = gate_w[c*1024+d]
// W1T[(ci*128+co)*12+tap] = sa_w1[(co*2048+ci)*9+tap] (tap<9, padded to 12)
__global__ void k_prep(const float* __restrict__ inw, const float* __restrict__ opw,
                       const float* __restrict__ gw, const float* __restrict__ saw1,
                       float* __restrict__ inWT, float* __restrict__ opWT,
                       float* __restrict__ gwT, float* __restrict__ W1T) {
  int idx = blockIdx.x * 256 + threadIdx.x;
  if (idx < 131072) {
    int c = idx >> 9, d = idx & 511;
    inWT[idx] = inw[d * 256 + c];
  } else if (idx < 262144) {
    int i = idx - 131072;
    int d = i >> 8, c = i & 255;
    opWT[i] = opw[c * 512 + d];
  } else if (idx < 786432) {
    int i = idx - 262144;
    int d = i >> 9, c = i & 511;
    gwT[i] = gw[c * 1024 + d];
  } else {
    int i = idx - 786432;            // 3,145,728 elems
    int tap = i % 12;
    int co  = (i / 12) & 127;
    int ci  = i / 1536;
    W1T[i] = (tap < 9) ? saw1[(co * 2048 + ci) * 9 + tap] : 0.f;
  }
}

// ---------------- in_proj: xz[b,d,p] = sum_c x[b,c,p]*W[d,c] ----------------
__global__ void __launch_bounds__(512) k_inproj(const float* __restrict__ x,
                                                const float* __restrict__ inWT,
                                                float* __restrict__ xz) {
  int d = threadIdx.x;           // 0..511
  int b = blockIdx.y;
  int p0 = blockIdx.x * 8;
  const float* xb = x + (size_t)(b * 256) * 1024 + p0;
  float acc[8];
#pragma unroll
  for (int j = 0; j < 8; ++j) acc[j] = 0.f;
  for (int c = 0; c < 256; ++c) {
    float w = inWT[c * 512 + d];
    const float* xr = xb + c * 1024;
    float4 a  = *(const float4*)xr;
    float4 b4 = *(const float4*)(xr + 4);
    acc[0] = fmaf(w, a.x,  acc[0]); acc[1] = fmaf(w, a.y,  acc[1]);
    acc[2] = fmaf(w, a.z,  acc[2]); acc[3] = fmaf(w, a.w,  acc[3]);
    acc[4] = fmaf(w, b4.x, acc[4]); acc[5] = fmaf(w, b4.y, acc[5]);
    acc[6] = fmaf(w, b4.z, acc[6]); acc[7] = fmaf(w, b4.w, acc[7]);
  }
  float* o = xz + (size_t)(b * 512 + d) * 1024 + p0;
  float4 o0 = {acc[0], acc[1], acc[2], acc[3]};
  float4 o1 = {acc[4], acc[5], acc[6], acc[7]};
  *(float4*)o = o0; *(float4*)(o + 4) = o1;
}

// ---------------- depthwise conv1d (K=4, pad 1/2) + SiLU, x-half ----------------
__global__ void k_convx(const float* __restrict__ xz, const float* __restrict__ cw,
                        const float* __restrict__ cb, float* __restrict__ xseq) {
  int l  = blockIdx.x * 256 + threadIdx.x;
  int rd = blockIdx.y; int r = rd >> 8; int d = rd & 255;
  int b  = blockIdx.z;
  float w0 = cw[rd*4+0], w1 = cw[rd*4+1], w2 = cw[rd*4+2], w3 = cw[rd*4+3];
  float acc = cb[rd];
  const float* src = xz + (size_t)(b * 512 + d) * 1024;
  if (l - 1 >= 0)   acc = fmaf(w0, src[srcmap(r, l - 1)], acc);
  acc = fmaf(w1, src[srcmap(r, l)], acc);
  if (l + 1 < 1024) acc = fmaf(w2, src[srcmap(r, l + 1)], acc);
  if (l + 2 < 1024) acc = fmaf(w3, src[srcmap(r, l + 2)], acc);
  xseq[((size_t)(b * 4 + r) * 256 + d) * 1024 + l] = siluf(acc);
}

// z-half: write silu(conv) un-rotated directly into Y channels [256..512)
__global__ void k_convz(const float* __restrict__ xz, const float* __restrict__ cw,
                        const float* __restrict__ cb, float* __restrict__ Y) {
  int l  = blockIdx.x * 256 + threadIdx.x;
  int rd = blockIdx.y; int r = rd >> 8; int d = rd & 255;
  int b  = blockIdx.z;
  float w0 = cw[rd*4+0], w1 = cw[rd*4+1], w2 = cw[rd*4+2], w3 = cw[rd*4+3];
  float acc = cb[rd];
  const float* src = xz + (size_t)(b * 512 + 256 + d) * 1024;
  if (l - 1 >= 0)   acc = fmaf(w0, src[srcmap(r, l - 1)], acc);
  acc = fmaf(w1, src[srcmap(r, l)], acc);
  if (l + 1 < 1024) acc = fmaf(w2, src[srcmap(r, l + 1)], acc);
  if (l + 2 < 1024) acc = fmaf(w3, src[srcmap(r, l + 2)], acc);
  Y[((size_t)(b * 4 + r) * 512 + 256 + d) * 1024 + srcmap(r, l)] = siluf(acc);
}

// ---------------- x_dbl[b,r,k,l] = sum_d xseq[b,r,d,l] * xpw[r,k,d] ----------------
__global__ void k_xdbl(const float* __restrict__ xseq, const float* __restrict__ xpw,
                       float* __restrict__ xdbl) {
  int l  = blockIdx.x * 256 + threadIdx.x;
  int k  = blockIdx.y;       // 0..47
  int br = blockIdx.z;       // b*4+r
  int r  = br & 3;
  const float* w  = xpw + (r * 48 + k) * 256;
  const float* xs = xseq + (size_t)(br * 256) * 1024 + l;
  float acc = 0.f;
  for (int d = 0; d < 256; ++d) acc = fmaf(w[d], xs[(size_t)d * 1024], acc);
  xdbl[((size_t)br * 48 + k) * 1024 + l] = acc;
}

// ---------------- selective scan (delta fused), writes un-rotated into Y [0..256) ----------------
__global__ void __launch_bounds__(256) k_scan(
    const float* __restrict__ xseq, const float* __restrict__ xdbl,
    const float* __restrict__ dtw_, const float* __restrict__ dtb_,
    const float* __restrict__ alogs, const float* __restrict__ ds_,
    float* __restrict__ Y) {
  int br = blockIdx.x; int r = br & 3;
  int d  = threadIdx.x;
  int rd = r * 256 + d;
  float dtw[16], A[16], h[16];
#pragma unroll
  for (int k = 0; k < 16; ++k) dtw[k] = dtw_[rd * 16 + k];
#pragma unroll
  for (int n = 0; n < 16; ++n) A[n] = -__expf(alogs[rd * 16 + n]);
#pragma unroll
  for (int n = 0; n < 16; ++n) h[n] = 0.f;
  float bias = dtb_[rd];
  float dsv  = ds_[rd];
  __shared__ float tile[48][64];
  const float* xd = xdbl + (size_t)(br * 48) * 1024;
  const float* us = xseq + (size_t)(br * 256 + d) * 1024;
  float* yo = Y + (size_t)(br * 512 + d) * 1024;
  for (int l0 = 0; l0 < 1024; l0 += 64) {
    __syncthreads();
    for (int idx = threadIdx.x; idx < 48 * 64; idx += 256) {
      int k = idx >> 6, c = idx & 63;
      tile[k][c] = xd[(size_t)k * 1024 + l0 + c];
    }
    __syncthreads();
    for (int c4 = 0; c4 < 16; ++c4) {
      float4 uv = *(const float4*)(us + l0 + c4 * 4);
      float uarr[4] = {uv.x, uv.y, uv.z, uv.w};
#pragma unroll
      for (int cc = 0; cc < 4; ++cc) {
        int c = c4 * 4 + cc;
        float u = uarr[cc];
        float delta = bias;
#pragma unroll
        for (int k = 0; k < 16; ++k) delta = fmaf(tile[k][c], dtw[k], delta);
        float sp = (delta > 20.f) ? delta : log1pf(__expf(delta));
        float du = sp * u;
        float acc = 0.f;
#pragma unroll
        for (int n = 0; n < 16; ++n) {
          float e = __expf(sp * A[n]);
          h[n] = fmaf(e, h[n], du * tile[16 + n][c]);
          acc  = fmaf(h[n], tile[32 + n][c], acc);
        }
        yo[srcmap(r, l0 + c)] = fmaf(dsv, u, acc);
      }
    }
  }
}

// ---------------- spatial attention 3x3 conv (2048 -> 128) + ReLU ----------------
__global__ void __launch_bounds__(256) k_saconv1(
    const float* __restrict__ Y, const float* __restrict__ W1T,
    const float* __restrict__ sab1, float* __restrict__ sa1) {
  int h = blockIdx.x, cog = blockIdx.y, b = blockIdx.z;
  int w    = threadIdx.x & 31;
  int slot = threadIdx.x >> 5;
  int co   = cog * 32 + slot * 4;
  const float* yb = Y + (size_t)(b * 2048) * 1024;
  float acc[4] = {0.f, 0.f, 0.f, 0.f};
  for (int ci = 0; ci < 2048; ++ci) {
    float yv[3][3];
#pragma unroll
    for (int dh = 0; dh < 3; ++dh) {
      int hh = h + dh - 1;
      if (hh < 0 || hh > 31) { yv[dh][0] = yv[dh][1] = yv[dh][2] = 0.f; }
      else {
        const float* yr = yb + (size_t)ci * 1024 + (hh << 5);
        yv[dh][0] = (w > 0)  ? yr[w - 1] : 0.f;
        yv[dh][1] = yr[w];
        yv[dh][2] = (w < 31) ? yr[w + 1] : 0.f;
      }
    }
    const float4* wp = (const float4*)(W1T + (size_t)(ci * 128 + co) * 12);
#pragma unroll
    for (int cc = 0; cc < 4; ++cc) {
      float4 wa = wp[cc * 3 + 0], wb = wp[cc * 3 + 1], wc = wp[cc * 3 + 2];
      float s;
      s  = yv[0][0] * wa.x + yv[0][1] * wa.y + yv[0][2] * wa.z;
      s += yv[1][0] * wa.w + yv[1][1] * wb.x + yv[1][2] * wb.y;
      s += yv[2][0] * wb.z + yv[2][1] * wb.w + yv[2][2] * wc.x;
      acc[cc] += s;
    }
  }
  int p = (h << 5) + w;
#pragma unroll
  for (int cc = 0; cc < 4; ++cc) {
    float v = acc[cc] + sab1[co + cc];
    sa1[((size_t)(b * 128) + co + cc) * 1024 + p] = fmaxf(v, 0.f);
  }
}

// ---------------- sa conv2 (128 -> 4) + softmax over R ----------------
__global__ void k_saconv2(const float* __restrict__ sa1, const float* __restrict__ saw2,
                          const float* __restrict__ sab2, float* __restrict__ swout) {
  int p = blockIdx.x * 256 + threadIdx.x;
  int b = blockIdx.y;
  float a0 = sab2[0], a1 = sab2[1], a2 = sab2[2], a3 = sab2[3];
  const float* s0 = sa1 + (size_t)(b * 128) * 1024 + p;
  for (int ci = 0; ci < 128; ++ci) {
    float s = s0[(size_t)ci * 1024];
    a0 = fmaf(s, saw2[ci],       a0);
    a1 = fmaf(s, saw2[128 + ci], a1);
    a2 = fmaf(s, saw2[256 + ci], a2);
    a3 = fmaf(s, saw2[384 + ci], a3);
  }
  float m = fmaxf(fmaxf(a0, a1), fmaxf(a2, a3));
  float e0 = __expf(a0 - m), e1 = __expf(a1 - m), e2 = __expf(a2 - m), e3 = __expf(a3 - m);
  float inv = 1.f / (e0 + e1 + e2 + e3);
  swout[(b * 4 + 0) * 1024 + p] = e0 * inv;
  swout[(b * 4 + 1) * 1024 + p] = e1 * inv;
  swout[(b * 4 + 2) * 1024 + p] = e2 * inv;
  swout[(b * 4 + 3) * 1024 + p] = e3 * inv;
}

// ---------------- channel avg over HW ----------------
__global__ void k_cavg(const float* __restrict__ Y, float* __restrict__ cavg) {
  int gid = blockIdx.x * 256 + threadIdx.x;   // b*2048 + ch
  const float4* yr = (const float4*)(Y + (size_t)gid * 1024);
  float s = 0.f;
  for (int i = 0; i < 256; ++i) {
    float4 v = yr[i];
    s += v.x + v.y + v.z + v.w;
  }
  cavg[gid] = s * (1.f / 1024.f);
}

// ---------------- channel attention MLP + softmax -> cw[b,4] ----------------
__global__ void k_cw(const float* __restrict__ cavg, const float* __restrict__ caw1,
                     const float* __restrict__ caw2, float* __restrict__ cwout) {
  int b = blockIdx.x;
  int t = threadIdx.x;
  __shared__ float hid[32];
  __shared__ float vv[4];
  if (t < 32) {
    float a = 0.f;
    const float* cv = cavg + b * 2048;
    const float* wr = caw1 + t * 2048;
    for (int i = 0; i < 2048; ++i) a = fmaf(wr[i], cv[i], a);
    hid[t] = fmaxf(a, 0.f);
  }
  __syncthreads();
  if (t < 4) {
    float a = 0.f;
    for (int i = 0; i < 32; ++i) a = fmaf(caw2[t * 32 + i], hid[i], a);
    vv[t] = a;
  }
  __syncthreads();
  if (t < 4) {
    float m = fmaxf(fmaxf(vv[0], vv[1]), fmaxf(vv[2], vv[3]));
    float e = __expf(vv[t] - m);
    float s = __expf(vv[0] - m) + __expf(vv[1] - m) + __expf(vv[2] - m) + __expf(vv[3] - m);
    cwout[b * 4 + t] = e / s;
  }
}

// ---------------- spatial & channel mixes ----------------
__global__ void k_spatialchannel(const float* __restrict__ Y, const float* __restrict__ swv,
                                 const float* __restrict__ cwv, float* __restrict__ spatial,
                                 float* __restrict__ channel) {
  int idx = blockIdx.x * 256 + threadIdx.x;
  int pq = idx & 255;
  int c  = (idx >> 8) & 511;
  int b  = idx >> 17;
  int p  = pq * 4;
  float sx=0,sy=0,sz=0,sw_=0, cx=0,cy=0,cz=0,cw_=0;
#pragma unroll
  for (int r = 0; r < 4; ++r) {
    float4 y = *(const float4*)(Y + ((size_t)(b * 4 + r) * 512 + c) * 1024 + p);
    float4 s = *(const float4*)(swv + (size_t)(b * 4 + r) * 1024 + p);
    float cr = cwv[b * 4 + r];
    sx = fmaf(y.x, s.x, sx); sy = fmaf(y.y, s.y, sy);
    sz = fmaf(y.z, s.z, sz); sw_ = fmaf(y.w, s.w, sw_);
    cx = fmaf(y.x, cr, cx); cy = fmaf(y.y, cr, cy);
    cz = fmaf(y.z, cr, cz); cw_ = fmaf(y.w, cr, cw_);
  }
  float4 so = {sx, sy, sz, sw_}, co = {cx, cy, cz, cw_};
  *(float4*)(spatial + ((size_t)(b * 512) + c) * 1024 + p) = so;
  *(float4*)(channel + ((size_t)(b * 512) + c) * 1024 + p) = co;
}

// ---------------- gate (1x1 conv 1024->512) + fuse ----------------
__global__ void __launch_bounds__(512) k_gate(
    const float* __restrict__ spatial, const float* __restrict__ channel,
    const float* __restrict__ gwT, const float* __restrict__ gb,
    float* __restrict__ fused) {
  int c  = threadIdx.x;     // 0..511
  int b  = blockIdx.y;
  int p0 = blockIdx.x * 8;
  const float* sp = spatial + (size_t)(b * 512) * 1024 + p0;
  const float* ch = channel + (size_t)(b * 512) * 1024 + p0;
  float acc[8];
#pragma unroll
  for (int j = 0; j < 8; ++j) acc[j] = 0.f;
  for (int d = 0; d < 512; ++d) {
    float w = gwT[d * 512 + c];
    const float* a = sp + (size_t)d * 1024;
    float4 v0 = *(const float4*)a, v1 = *(const float4*)(a + 4);
    acc[0]=fmaf(w,v0.x,acc[0]); acc[1]=fmaf(w,v0.y,acc[1]);
    acc[2]=fmaf(w,v0.z,acc[2]); acc[3]=fmaf(w,v0.w,acc[3]);
    acc[4]=fmaf(w,v1.x,acc[4]); acc[5]=fmaf(w,v1.y,acc[5]);
    acc[6]=fmaf(w,v1.z,acc[6]); acc[7]=fmaf(w,v1.w,acc[7]);
  }
  for (int d = 0; d < 512; ++d) {
    float w = gwT[(512 + d) * 512 + c];
    const float* a = ch + (size_t)d * 1024;
    float4 v0 = *(const float4*)a, v1 = *(const float4*)(a + 4);
    acc[0]=fmaf(w,v0.x,acc[0]); acc[1]=fmaf(w,v0.y,acc[1]);
    acc[2]=fmaf(w,v0.z,acc[2]); acc[3]=fmaf(w,v0.w,acc[3]);
    acc[4]=fmaf(w,v1.x,acc[4]); acc[5]=fmaf(w,v1.y,acc[5]);
    acc[6]=fmaf(w,v1.z,acc[6]); acc[7]=fmaf(w,v1.w,acc[7]);
  }
  float bias = gb[c];
  const float* spc = sp + (size_t)c * 1024;
  const float* chc = ch + (size_t)c * 1024;
  float* fo = fused + ((size_t)(b * 512) + c) * 1024 + p0;
#pragma unroll
  for (int j = 0; j < 8; ++j) {
    float g = sigmoidf_(acc[j] + bias);
    fo[j] = g * spc[j] + (1.f - g) * chc[j];
  }
}

// ---------------- out_proj (512->256) + GELU ----------------
__global__ void k_outproj(const float* __restrict__ fused, const float* __restrict__ opWT,
                          float* __restrict__ out) {
  int co = threadIdx.x;     // 0..255
  int b  = blockIdx.y;
  int p0 = blockIdx.x * 8;
  const float* fb = fused + (size_t)(b * 512) * 1024 + p0;
  float acc[8];
#pragma unroll
  for (int j = 0; j < 8; ++j) acc[j] = 0.f;
  for (int d = 0; d < 512; ++d) {
    float w = opWT[d * 256 + co];
    const float* a = fb + (size_t)d * 1024;
    float4 v0 = *(const float4*)a, v1 = *(const float4*)(a + 4);
    acc[0]=fmaf(w,v0.x,acc[0]); acc[1]=fmaf(w,v0.y,acc[1]);
    acc[2]=fmaf(w,v0.z,acc[2]); acc[3]=fmaf(w,v0.w,acc[3]);
    acc[4]=fmaf(w,v1.x,acc[4]); acc[5]=fmaf(w,v1.y,acc[5]);
    acc[6]=fmaf(w,v1.z,acc[6]); acc[7]=fmaf(w,v1.w,acc[7]);
  }
  float* o = out + ((size_t)(b * 256) + co) * 1024 + p0;
#pragma unroll
  for (int j = 0; j < 8; ++j) o[j] = geluf(acc[j]);
}

extern "C" void kernel_launch(void* const* d_in, const int* in_sizes, int n_in,
                              void* d_out, int out_size, void* d_ws, size_t ws_size,
                              hipStream_t stream) {
  const float* x    = (const float*)d_in[0];
  const float* inw  = (const float*)d_in[1];
  const float* opw  = (const float*)d_in[2];
  const float* cxw  = (const float*)d_in[3];
  const float* cxb  = (const float*)d_in[4];
  const float* czw  = (const float*)d_in[5];
  const float* czb  = (const float*)d_in[6];
  const float* xpw  = (const float*)d_in[7];
  const float* dtw  = (const float*)d_in[8];
  const float* dtb  = (const float*)d_in[9];
  const float* alog = (const float*)d_in[10];
  const float* ds   = (const float*)d_in[11];
  const float* saw1 = (const float*)d_in[12];
  const float* sab1 = (const float*)d_in[13];
  const float* saw2 = (const float*)d_in[14];
  const float* sab2 = (const float*)d_in[15];
  const float* caw1 = (const float*)d_in[16];
  const float* caw2 = (const float*)d_in[17];
  const float* gw   = (const float*)d_in[18];
  const float* gb   = (const float*)d_in[19];

  float* ws = (float*)d_ws;
  // workspace layout (floats); total = 35,962,912 floats = 143.9 MB
  float* xz   = ws + 0;          //  4,194,304 (b,512,1024)   [reused as fused]
  float* xseq = ws + 4194304;    //  8,388,608 (b,4,256,1024) [reused as spatial|channel]
  float* xdbl = ws + 12582912;   //  1,572,864 (b,4,48,1024)
  float* Y    = ws + 14155776;   // 16,777,216 (b,4,512,1024) un-rotated
  float* sa1  = ws + 30932992;   //  1,048,576 (b,128,1024)
  float* swb  = ws + 31981568;   //     32,768 (b,4,1024)
  float* cavg = ws + 32014336;   //     16,384 (b,2048)
  float* cwb  = ws + 32030720;   //         32 (b,4)
  float* inWT = ws + 32030752;   //    131,072
  float* opWT = ws + 32161824;   //    131,072
  float* gwT  = ws + 32292896;   //    524,288
  float* W1T  = ws + 32817184;   //  3,145,728
  float* spatial = xseq;
  float* channel = xseq + 4194304;
  float* fused   = xz;

  k_prep<<<15360, 256, 0, stream>>>(inw, opw, gw, saw1, inWT, opWT, gwT, W1T);
  k_inproj<<<dim3(128, 8), 512, 0, stream>>>(x, inWT, xz);
  k_convx<<<dim3(4, 1024, 8), 256, 0, stream>>>(xz, cxw, cxb, xseq);
  k_convz<<<dim3(4, 1024, 8), 256, 0, stream>>>(xz, czw, czb, Y);
  k_xdbl<<<dim3(4, 48, 32), 256, 0, stream>>>(xseq, xpw, xdbl);
  k_scan<<<32, 256, 0, stream>>>(xseq, xdbl, dtw, dtb, alog, ds, Y);
  k_saconv1<<<dim3(32, 4, 8), 256, 0, stream>>>(Y, W1T, sab1, sa1);
  k_saconv2<<<dim3(4, 8), 256, 0, stream>>>(sa1, saw2, sab2, swb);
  k_cavg<<<64, 256, 0, stream>>>(Y, cavg);
  k_cw<<<8, 64, 0, stream>>>(cavg, caw1, caw2, cwb);
  k_spatialchannel<<<4096, 256, 0, stream>>>(Y, swb, cwb, spatial, channel);
  k_gate<<<dim3(128, 8), 512, 0, stream>>>(spatial, channel, gwT, gb, fused);
  k_outproj<<<dim3(128, 8), 256, 0, stream>>>(fused, opWT, (float*)d_out);
}

// Round 2
// 1406.394 us; speedup vs baseline: 2.7968x; 2.7968x over previous
//
#include <hip/hip_runtime.h>
#include <math.h>

// dims: B=8, DM=256, H=W=32, L=HW=1024, R=4, DI=512, DH=256, N=16, K=4, DTR=16

typedef _Float16 half8 __attribute__((ext_vector_type(8)));
typedef float f4 __attribute__((ext_vector_type(4)));

__device__ __forceinline__ int srcmap(int r, int l) {
  int i = l >> 5, j = l & 31;
  int h, w;
  if (r == 0)      { h = i;      w = j;      }
  else if (r == 1) { h = j;      w = 31 - i; }
  else if (r == 2) { h = 31 - i; w = 31 - j; }
  else             { h = 31 - j; w = i;      }
  return (h << 5) + w;
}

__device__ __forceinline__ float siluf(float x)    { return x / (1.f + __expf(-x)); }
__device__ __forceinline__ float sigmoidf_(float x){ return 1.f / (1.f + __expf(-x)); }
__device__ __forceinline__ float geluf(float x) {
  float x3 = x * x * x;
  return 0.5f * x * (1.f + tanhf(0.7978845608028654f * (x + 0.044715f * x3)));
}

// ---------------- weight pre-transposes (inWT, opWT, gwT) ----------------
__global__ void k_prep(const float* __restrict__ inw, const float* __restrict__ opw,
                       const float* __restrict__ gw,
                       float* __restrict__ inWT, float* __restrict__ opWT,
                       float* __restrict__ gwT) {
  int idx = blockIdx.x * 256 + threadIdx.x;
  if (idx < 131072) {
    int c = idx >> 9, d = idx & 511;
    inWT[idx] = inw[d * 256 + c];
  } else if (idx < 262144) {
    int i = idx - 131072;
    int d = i >> 8, c = i & 255;
    opWT[i] = opw[c * 512 + d];
  } else {
    int i = idx - 262144;
    int d = i >> 9, c = i & 511;
    gwT[i] = gw[c * 1024 + d];
  }
}

// ---------------- fp16 pack of sa_w1: Whg[tap][co][ci] ----------------
__global__ void k_wprep(const float* __restrict__ saw1, _Float16* __restrict__ Whg) {
  int o = blockIdx.x * 256 + threadIdx.x;           // < 2,359,296
  int ci = o & 2047;
  int co = (o >> 11) & 127;
  int tap = o >> 18;
  Whg[o] = (_Float16)saw1[((size_t)co * 2048 + ci) * 9 + tap];
}

// ---------------- in_proj ----------------
__global__ void __launch_bounds__(512) k_inproj(const float* __restrict__ x,
                                                const float* __restrict__ inWT,
                                                float* __restrict__ xz) {
  int d = threadIdx.x;
  int b = blockIdx.y;
  int p0 = blockIdx.x * 8;
  const float* xb = x + (size_t)(b * 256) * 1024 + p0;
  float acc[8];
#pragma unroll
  for (int j = 0; j < 8; ++j) acc[j] = 0.f;
  for (int c = 0; c < 256; ++c) {
    float w = inWT[c * 512 + d];
    const float* xr = xb + c * 1024;
    float4 a  = *(const float4*)xr;
    float4 b4 = *(const float4*)(xr + 4);
    acc[0] = fmaf(w, a.x,  acc[0]); acc[1] = fmaf(w, a.y,  acc[1]);
    acc[2] = fmaf(w, a.z,  acc[2]); acc[3] = fmaf(w, a.w,  acc[3]);
    acc[4] = fmaf(w, b4.x, acc[4]); acc[5] = fmaf(w, b4.y, acc[5]);
    acc[6] = fmaf(w, b4.z, acc[6]); acc[7] = fmaf(w, b4.w, acc[7]);
  }
  float* o = xz + (size_t)(b * 512 + d) * 1024 + p0;
  float4 o0 = {acc[0], acc[1], acc[2], acc[3]};
  float4 o1 = {acc[4], acc[5], acc[6], acc[7]};
  *(float4*)o = o0; *(float4*)(o + 4) = o1;
}

// ---------------- depthwise conv1d + SiLU (x-half) ----------------
__global__ void k_convx(const float* __restrict__ xz, const float* __restrict__ cw,
                        const float* __restrict__ cb, float* __restrict__ xseq) {
  int l  = blockIdx.x * 256 + threadIdx.x;
  int rd = blockIdx.y; int r = rd >> 8; int d = rd & 255;
  int b  = blockIdx.z;
  float w0 = cw[rd*4+0], w1 = cw[rd*4+1], w2 = cw[rd*4+2], w3 = cw[rd*4+3];
  float acc = cb[rd];
  const float* src = xz + (size_t)(b * 512 + d) * 1024;
  if (l - 1 >= 0)   acc = fmaf(w0, src[srcmap(r, l - 1)], acc);
  acc = fmaf(w1, src[srcmap(r, l)], acc);
  if (l + 1 < 1024) acc = fmaf(w2, src[srcmap(r, l + 1)], acc);
  if (l + 2 < 1024) acc = fmaf(w3, src[srcmap(r, l + 2)], acc);
  xseq[((size_t)(b * 4 + r) * 256 + d) * 1024 + l] = siluf(acc);
}

// z-half -> un-rotated into Y channels [256..512)
__global__ void k_convz(const float* __restrict__ xz, const float* __restrict__ cw,
                        const float* __restrict__ cb, float* __restrict__ Y) {
  int l  = blockIdx.x * 256 + threadIdx.x;
  int rd = blockIdx.y; int r = rd >> 8; int d = rd & 255;
  int b  = blockIdx.z;
  float w0 = cw[rd*4+0], w1 = cw[rd*4+1], w2 = cw[rd*4+2], w3 = cw[rd*4+3];
  float acc = cb[rd];
  const float* src = xz + (size_t)(b * 512 + 256 + d) * 1024;
  if (l - 1 >= 0)   acc = fmaf(w0, src[srcmap(r, l - 1)], acc);
  acc = fmaf(w1, src[srcmap(r, l)], acc);
  if (l + 1 < 1024) acc = fmaf(w2, src[srcmap(r, l + 1)], acc);
  if (l + 2 < 1024) acc = fmaf(w3, src[srcmap(r, l + 2)], acc);
  Y[((size_t)(b * 4 + r) * 512 + 256 + d) * 1024 + srcmap(r, l)] = siluf(acc);
}

// ---------------- x_dbl ----------------
__global__ void k_xdbl(const float* __restrict__ xseq, const float* __restrict__ xpw,
                       float* __restrict__ xdbl) {
  int l  = blockIdx.x * 256 + threadIdx.x;
  int k  = blockIdx.y;
  int br = blockIdx.z;
  int r  = br & 3;
  const float* w  = xpw + (r * 48 + k) * 256;
  const float* xs = xseq + (size_t)(br * 256) * 1024 + l;
  float acc = 0.f;
  for (int d = 0; d < 256; ++d) acc = fmaf(w[d], xs[(size_t)d * 1024], acc);
  xdbl[((size_t)br * 48 + k) * 1024 + l] = acc;
}

// ---------------- selective scan ----------------
__global__ void __launch_bounds__(256) k_scan(
    const float* __restrict__ xseq, const float* __restrict__ xdbl,
    const float* __restrict__ dtw_, const float* __restrict__ dtb_,
    const float* __restrict__ alogs, const float* __restrict__ ds_,
    float* __restrict__ Y) {
  int br = blockIdx.x; int r = br & 3;
  int d  = threadIdx.x;
  int rd = r * 256 + d;
  float dtw[16], A[16], h[16];
#pragma unroll
  for (int k = 0; k < 16; ++k) dtw[k] = dtw_[rd * 16 + k];
#pragma unroll
  for (int n = 0; n < 16; ++n) A[n] = -__expf(alogs[rd * 16 + n]);
#pragma unroll
  for (int n = 0; n < 16; ++n) h[n] = 0.f;
  float bias = dtb_[rd];
  float dsv  = ds_[rd];
  __shared__ float tile[48][64];
  const float* xd = xdbl + (size_t)(br * 48) * 1024;
  const float* us = xseq + (size_t)(br * 256 + d) * 1024;
  float* yo = Y + (size_t)(br * 512 + d) * 1024;
  for (int l0 = 0; l0 < 1024; l0 += 64) {
    __syncthreads();
    for (int idx = threadIdx.x; idx < 48 * 64; idx += 256) {
      int k = idx >> 6, c = idx & 63;
      tile[k][c] = xd[(size_t)k * 1024 + l0 + c];
    }
    __syncthreads();
    for (int c4 = 0; c4 < 16; ++c4) {
      float4 uv = *(const float4*)(us + l0 + c4 * 4);
      float uarr[4] = {uv.x, uv.y, uv.z, uv.w};
#pragma unroll
      for (int cc = 0; cc < 4; ++cc) {
        int c = c4 * 4 + cc;
        float u = uarr[cc];
        float delta = bias;
#pragma unroll
        for (int k = 0; k < 16; ++k) delta = fmaf(tile[k][c], dtw[k], delta);
        float sp = (delta > 20.f) ? delta : log1pf(__expf(delta));
        float du = sp * u;
        float acc = 0.f;
#pragma unroll
        for (int n = 0; n < 16; ++n) {
          float e = __expf(sp * A[n]);
          h[n] = fmaf(e, h[n], du * tile[16 + n][c]);
          acc  = fmaf(h[n], tile[32 + n][c], acc);
        }
        yo[srcmap(r, l0 + c)] = fmaf(dsv, u, acc);
      }
    }
  }
}

// ---------------- Y -> fp16 transposed Ytg[b][pix][ci] ----------------
__global__ void k_ytr(const float* __restrict__ Y, _Float16* __restrict__ Ytg) {
  __shared__ float t[32][132];
  int p0  = blockIdx.x * 128;
  int ci0 = blockIdx.y * 32;
  int b   = blockIdx.z;
  const float* src = Y + ((size_t)(b * 2048 + ci0)) * 1024 + p0;
#pragma unroll
  for (int i = 0; i < 16; ++i) {
    int idx = threadIdx.x + i * 256;
    int ci = idx >> 7, pp = idx & 127;
    t[ci][pp] = src[(size_t)ci * 1024 + pp];
  }
  __syncthreads();
  int pp = threadIdx.x >> 1;
  int ch = (threadIdx.x & 1) * 16;
  _Float16 buf[16];
#pragma unroll
  for (int j = 0; j < 16; ++j) buf[j] = (_Float16)t[ch + j][pp];
  _Float16* dst = Ytg + ((size_t)(b * 1024) + p0 + pp) * 2048 + ci0 + ch;
  *(float4*)dst = *(const float4*)buf;
  *(float4*)(dst + 8) = *(const float4*)(buf + 8);
}

// ---------------- spatial-attn conv1 via MFMA (implicit GEMM, split-K=4) ----------------
// grid (64 mblk, 2 nblk, 4 ksplit), block 128 (2 waves); wave tile = 64 pix x 64 co
__global__ void __launch_bounds__(128) k_samfma(const _Float16* __restrict__ Ytg,
                                                const _Float16* __restrict__ Whg,
                                                float* __restrict__ cpart) {
  int wid = threadIdx.x >> 6, lane = threadIdx.x & 63;
  int r = lane & 15, g = lane >> 4;
  int mblk = blockIdx.x;
  int b = mblk >> 3;
  int rowbase = (mblk & 7) * 4 + wid * 2;      // first image row of this wave
  int n0 = blockIdx.y * 64;
  int k0 = blockIdx.z * 512;
  const _Float16* Yb = Ytg + (size_t)b * (1024 * 2048);
  f4 acc[4][4];
#pragma unroll
  for (int mi = 0; mi < 4; ++mi)
#pragma unroll
    for (int ni = 0; ni < 4; ++ni) acc[mi][ni] = (f4){0.f, 0.f, 0.f, 0.f};
  const half8 zero8 = {0, 0, 0, 0, 0, 0, 0, 0};

  for (int kc = 0; kc < 16; ++kc) {
    int ci = k0 + kc * 32 + g * 8;
#pragma unroll
    for (int tap = 0; tap < 9; ++tap) {
      const int dh = tap / 3 - 1, dw = tap % 3 - 1;
      half8 av[4], bv[4];
#pragma unroll
      for (int mi = 0; mi < 4; ++mi) {
        int pr = rowbase + ((mi * 16 + r) >> 5) + dh;
        int pc = ((mi * 16 + r) & 31) + dw;
        bool ok = ((unsigned)pr < 32u) && ((unsigned)pc < 32u);
        const _Float16* ap = Yb + (size_t)((ok ? pr : 0) * 32 + (ok ? pc : 0)) * 2048 + ci;
        half8 v = *(const half8*)ap;
        av[mi] = ok ? v : zero8;
      }
#pragma unroll
      for (int ni = 0; ni < 4; ++ni) {
        int co = n0 + ni * 16 + r;
        bv[ni] = *(const half8*)(Whg + (size_t)(tap * 128 + co) * 2048 + ci);
      }
#pragma unroll
      for (int mi = 0; mi < 4; ++mi)
#pragma unroll
        for (int ni = 0; ni < 4; ++ni)
          acc[mi][ni] = __builtin_amdgcn_mfma_f32_16x16x32_f16(av[mi], bv[ni], acc[mi][ni], 0, 0, 0);
    }
  }
  float* cp = cpart + (size_t)blockIdx.z * (8192 * 128);
  int basepix = b * 1024 + rowbase * 32;
#pragma unroll
  for (int mi = 0; mi < 4; ++mi)
#pragma unroll
    for (int ni = 0; ni < 4; ++ni) {
      int co = n0 + ni * 16 + r;
#pragma unroll
      for (int j = 0; j < 4; ++j)
        cp[(size_t)(basepix + mi * 16 + g * 4 + j) * 128 + co] = acc[mi][ni][j];
    }
}

// ---------------- reduce partials + bias + relu + conv2 + softmax ----------------
__global__ void k_saconv2f(const float* __restrict__ cpart, const float* __restrict__ sab1,
                           const float* __restrict__ saw2, const float* __restrict__ sab2,
                           float* __restrict__ swout) {
  int p = blockIdx.x * 256 + threadIdx.x;  // 0..1023
  int b = blockIdx.y;
  int pix = b * 1024 + p;
  const float* c0 = cpart + (size_t)pix * 128;
  float a0 = sab2[0], a1 = sab2[1], a2 = sab2[2], a3 = sab2[3];
  for (int ci = 0; ci < 128; ++ci) {
    float s = c0[ci] + c0[ci + 1048576] + c0[ci + 2097152] + c0[ci + 3145728];
    float v = fmaxf(s + sab1[ci], 0.f);
    a0 = fmaf(v, saw2[ci],       a0);
    a1 = fmaf(v, saw2[128 + ci], a1);
    a2 = fmaf(v, saw2[256 + ci], a2);
    a3 = fmaf(v, saw2[384 + ci], a3);
  }
  float m = fmaxf(fmaxf(a0, a1), fmaxf(a2, a3));
  float e0 = __expf(a0 - m), e1 = __expf(a1 - m), e2 = __expf(a2 - m), e3 = __expf(a3 - m);
  float inv = 1.f / (e0 + e1 + e2 + e3);
  swout[(b * 4 + 0) * 1024 + p] = e0 * inv;
  swout[(b * 4 + 1) * 1024 + p] = e1 * inv;
  swout[(b * 4 + 2) * 1024 + p] = e2 * inv;
  swout[(b * 4 + 3) * 1024 + p] = e3 * inv;
}

// ---------------- channel avg ----------------
__global__ void k_cavg(const float* __restrict__ Y, float* __restrict__ cavg) {
  int gid = blockIdx.x * 256 + threadIdx.x;
  const float4* yr = (const float4*)(Y + (size_t)gid * 1024);
  float s = 0.f;
  for (int i = 0; i < 256; ++i) {
    float4 v = yr[i];
    s += v.x + v.y + v.z + v.w;
  }
  cavg[gid] = s * (1.f / 1024.f);
}

// ---------------- channel attention ----------------
__global__ void k_cw(const float* __restrict__ cavg, const float* __restrict__ caw1,
                     const float* __restrict__ caw2, float* __restrict__ cwout) {
  int b = blockIdx.x;
  int t = threadIdx.x;
  __shared__ float hid[32];
  __shared__ float vv[4];
  if (t < 32) {
    float a = 0.f;
    const float* cv = cavg + b * 2048;
    const float* wr = caw1 + t * 2048;
    for (int i = 0; i < 2048; ++i) a = fmaf(wr[i], cv[i], a);
    hid[t] = fmaxf(a, 0.f);
  }
  __syncthreads();
  if (t < 4) {
    float a = 0.f;
    for (int i = 0; i < 32; ++i) a = fmaf(caw2[t * 32 + i], hid[i], a);
    vv[t] = a;
  }
  __syncthreads();
  if (t < 4) {
    float m = fmaxf(fmaxf(vv[0], vv[1]), fmaxf(vv[2], vv[3]));
    float e = __expf(vv[t] - m);
    float s = __expf(vv[0] - m) + __expf(vv[1] - m) + __expf(vv[2] - m) + __expf(vv[3] - m);
    cwout[b * 4 + t] = e / s;
  }
}

// ---------------- spatial & channel mixes ----------------
__global__ void k_spatialchannel(const float* __restrict__ Y, const float* __restrict__ swv,
                                 const float* __restrict__ cwv, float* __restrict__ spatial,
                                 float* __restrict__ channel) {
  int idx = blockIdx.x * 256 + threadIdx.x;
  int pq = idx & 255;
  int c  = (idx >> 8) & 511;
  int b  = idx >> 17;
  int p  = pq * 4;
  float sx=0,sy=0,sz=0,sw_=0, cx=0,cy=0,cz=0,cw_=0;
#pragma unroll
  for (int r = 0; r < 4; ++r) {
    float4 y = *(const float4*)(Y + ((size_t)(b * 4 + r) * 512 + c) * 1024 + p);
    float4 s = *(const float4*)(swv + (size_t)(b * 4 + r) * 1024 + p);
    float cr = cwv[b * 4 + r];
    sx = fmaf(y.x, s.x, sx); sy = fmaf(y.y, s.y, sy);
    sz = fmaf(y.z, s.z, sz); sw_ = fmaf(y.w, s.w, sw_);
    cx = fmaf(y.x, cr, cx); cy = fmaf(y.y, cr, cy);
    cz = fmaf(y.z, cr, cz); cw_ = fmaf(y.w, cr, cw_);
  }
  float4 so = {sx, sy, sz, sw_}, co = {cx, cy, cz, cw_};
  *(float4*)(spatial + ((size_t)(b * 512) + c) * 1024 + p) = so;
  *(float4*)(channel + ((size_t)(b * 512) + c) * 1024 + p) = co;
}

// ---------------- gate + fuse ----------------
__global__ void __launch_bounds__(512) k_gate(
    const float* __restrict__ spatial, const float* __restrict__ channel,
    const float* __restrict__ gwT, const float* __restrict__ gb,
    float* __restrict__ fused) {
  int c  = threadIdx.x;
  int b  = blockIdx.y;
  int p0 = blockIdx.x * 8;
  const float* sp = spatial + (size_t)(b * 512) * 1024 + p0;
  const float* ch = channel + (size_t)(b * 512) * 1024 + p0;
  float acc[8];
#pragma unroll
  for (int j = 0; j < 8; ++j) acc[j] = 0.f;
  for (int d = 0; d < 512; ++d) {
    float w = gwT[d * 512 + c];
    const float* a = sp + (size_t)d * 1024;
    float4 v0 = *(const float4*)a, v1 = *(const float4*)(a + 4);
    acc[0]=fmaf(w,v0.x,acc[0]); acc[1]=fmaf(w,v0.y,acc[1]);
    acc[2]=fmaf(w,v0.z,acc[2]); acc[3]=fmaf(w,v0.w,acc[3]);
    acc[4]=fmaf(w,v1.x,acc[4]); acc[5]=fmaf(w,v1.y,acc[5]);
    acc[6]=fmaf(w,v1.z,acc[6]); acc[7]=fmaf(w,v1.w,acc[7]);
  }
  for (int d = 0; d < 512; ++d) {
    float w = gwT[(512 + d) * 512 + c];
    const float* a = ch + (size_t)d * 1024;
    float4 v0 = *(const float4*)a, v1 = *(const float4*)(a + 4);
    acc[0]=fmaf(w,v0.x,acc[0]); acc[1]=fmaf(w,v0.y,acc[1]);
    acc[2]=fmaf(w,v0.z,acc[2]); acc[3]=fmaf(w,v0.w,acc[3]);
    acc[4]=fmaf(w,v1.x,acc[4]); acc[5]=fmaf(w,v1.y,acc[5]);
    acc[6]=fmaf(w,v1.z,acc[6]); acc[7]=fmaf(w,v1.w,acc[7]);
  }
  float bias = gb[c];
  const float* spc = sp + (size_t)c * 1024;
  const float* chc = ch + (size_t)c * 1024;
  float* fo = fused + ((size_t)(b * 512) + c) * 1024 + p0;
#pragma unroll
  for (int j = 0; j < 8; ++j) {
    float g = sigmoidf_(acc[j] + bias);
    fo[j] = g * spc[j] + (1.f - g) * chc[j];
  }
}

// ---------------- out_proj + GELU ----------------
__global__ void k_outproj(const float* __restrict__ fused, const float* __restrict__ opWT,
                          float* __restrict__ out) {
  int co = threadIdx.x;
  int b  = blockIdx.y;
  int p0 = blockIdx.x * 8;
  const float* fb = fused + (size_t)(b * 512) * 1024 + p0;
  float acc[8];
#pragma unroll
  for (int j = 0; j < 8; ++j) acc[j] = 0.f;
  for (int d = 0; d < 512; ++d) {
    float w = opWT[d * 256 + co];
    const float* a = fb + (size_t)d * 1024;
    float4 v0 = *(const float4*)a, v1 = *(const float4*)(a + 4);
    acc[0]=fmaf(w,v0.x,acc[0]); acc[1]=fmaf(w,v0.y,acc[1]);
    acc[2]=fmaf(w,v0.z,acc[2]); acc[3]=fmaf(w,v0.w,acc[3]);
    acc[4]=fmaf(w,v1.x,acc[4]); acc[5]=fmaf(w,v1.y,acc[5]);
    acc[6]=fmaf(w,v1.z,acc[6]); acc[7]=fmaf(w,v1.w,acc[7]);
  }
  float* o = out + ((size_t)(b * 256) + co) * 1024 + p0;
#pragma unroll
  for (int j = 0; j < 8; ++j) o[j] = geluf(acc[j]);
}

extern "C" void kernel_launch(void* const* d_in, const int* in_sizes, int n_in,
                              void* d_out, int out_size, void* d_ws, size_t ws_size,
                              hipStream_t stream) {
  const float* x    = (const float*)d_in[0];
  const float* inw  = (const float*)d_in[1];
  const float* opw  = (const float*)d_in[2];
  const float* cxw  = (const float*)d_in[3];
  const float* cxb  = (const float*)d_in[4];
  const float* czw  = (const float*)d_in[5];
  const float* czb  = (const float*)d_in[6];
  const float* xpw  = (const float*)d_in[7];
  const float* dtw  = (const float*)d_in[8];
  const float* dtb  = (const float*)d_in[9];
  const float* alog = (const float*)d_in[10];
  const float* ds   = (const float*)d_in[11];
  const float* saw1 = (const float*)d_in[12];
  const float* sab1 = (const float*)d_in[13];
  const float* saw2 = (const float*)d_in[14];
  const float* sab2 = (const float*)d_in[15];
  const float* caw1 = (const float*)d_in[16];
  const float* caw2 = (const float*)d_in[17];
  const float* gw   = (const float*)d_in[18];
  const float* gb   = (const float*)d_in[19];

  float* ws = (float*)d_ws;
  // workspace layout (floats); total = 33,996,832 floats = 136.0 MB
  float* xz   = ws + 0;          //  4,194,304  [alias: Cpart (4x8192x128), then fused]
  float* xseq = ws + 4194304;    //  8,388,608  [alias: Ytg fp16 (16.8M halves), then spatial|channel]
  float* xdbl = ws + 12582912;   //  1,572,864
  float* Y    = ws + 14155776;   // 16,777,216
  float* sa1  = ws + 30932992;   //  1,048,576  (unused this round)
  float* swb  = ws + 31981568;   //     32,768
  float* cavg = ws + 32014336;   //     16,384
  float* cwb  = ws + 32030720;   //         32
  float* inWT = ws + 32030752;   //    131,072
  float* opWT = ws + 32161824;   //    131,072
  float* gwT  = ws + 32292896;   //    524,288
  float* WhgF = ws + 32817184;   //  1,179,648  (Whg fp16: 2,359,296 halves)
  (void)sa1;
  float* Cpart = xz;
  _Float16* Ytg = (_Float16*)xseq;
  _Float16* Whg = (_Float16*)WhgF;
  float* spatial = xseq;
  float* channel = xseq + 4194304;
  float* fused   = xz;

  k_prep<<<3072, 256, 0, stream>>>(inw, opw, gw, inWT, opWT, gwT);
  k_wprep<<<9216, 256, 0, stream>>>(saw1, Whg);
  k_inproj<<<dim3(128, 8), 512, 0, stream>>>(x, inWT, xz);
  k_convx<<<dim3(4, 1024, 8), 256, 0, stream>>>(xz, cxw, cxb, xseq);
  k_convz<<<dim3(4, 1024, 8), 256, 0, stream>>>(xz, czw, czb, Y);
  k_xdbl<<<dim3(4, 48, 32), 256, 0, stream>>>(xseq, xpw, xdbl);
  k_scan<<<32, 256, 0, stream>>>(xseq, xdbl, dtw, dtb, alog, ds, Y);
  k_ytr<<<dim3(8, 64, 8), 256, 0, stream>>>(Y, Ytg);
  k_samfma<<<dim3(64, 2, 4), 128, 0, stream>>>(Ytg, Whg, Cpart);
  k_saconv2f<<<dim3(4, 8), 256, 0, stream>>>(Cpart, sab1, saw2, sab2, swb);
  k_cavg<<<64, 256, 0, stream>>>(Y, cavg);
  k_cw<<<8, 64, 0, stream>>>(cavg, caw1, caw2, cwb);
  k_spatialchannel<<<4096, 256, 0, stream>>>(Y, swb, cwb, spatial, channel);
  k_gate<<<dim3(128, 8), 512, 0, stream>>>(spatial, channel, gwT, gb, fused);
  k_outproj<<<dim3(128, 8), 256, 0, stream>>>(fused, opWT, (float*)d_out);
}

// Round 3
// 898.173 us; speedup vs baseline: 4.3794x; 1.5658x over previous
//
#include <hip/hip_runtime.h>
#include <math.h>

// dims: B=8, DM=256, H=W=32, L=HW=1024, R=4, DI=512, DH=256, N=16, K=4, DTR=16

typedef _Float16 half8 __attribute__((ext_vector_type(8)));
typedef float f4 __attribute__((ext_vector_type(4)));

__device__ __forceinline__ int srcmap(int r, int l) {
  int i = l >> 5, j = l & 31;
  int h, w;
  if (r == 0)      { h = i;      w = j;      }
  else if (r == 1) { h = j;      w = 31 - i; }
  else if (r == 2) { h = 31 - i; w = 31 - j; }
  else             { h = 31 - j; w = i;      }
  return (h << 5) + w;
}

__device__ __forceinline__ float siluf(float x)    { return x / (1.f + __expf(-x)); }
__device__ __forceinline__ float sigmoidf_(float x){ return 1.f / (1.f + __expf(-x)); }
__device__ __forceinline__ float geluf(float x) {
  float x3 = x * x * x;
  return 0.5f * x * (1.f + tanhf(0.7978845608028654f * (x + 0.044715f * x3)));
}

// ---------------- weight pre-transposes (inWT, opWT, gwT) ----------------
__global__ void k_prep(const float* __restrict__ inw, const float* __restrict__ opw,
                       const float* __restrict__ gw,
                       float* __restrict__ inWT, float* __restrict__ opWT,
                       float* __restrict__ gwT) {
  int idx = blockIdx.x * 256 + threadIdx.x;
  if (idx < 131072) {
    int c = idx >> 9, d = idx & 511;
    inWT[idx] = inw[d * 256 + c];
  } else if (idx < 262144) {
    int i = idx - 131072;
    int d = i >> 8, c = i & 255;
    opWT[i] = opw[c * 512 + d];
  } else {
    int i = idx - 262144;
    int d = i >> 9, c = i & 511;
    gwT[i] = gw[c * 1024 + d];
  }
}

// ---------------- fp16 pack of sa_w1: Whg[tap][co][ci] ----------------
__global__ void k_wprep(const float* __restrict__ saw1, _Float16* __restrict__ Whg) {
  int o = blockIdx.x * 256 + threadIdx.x;           // < 2,359,296
  int ci = o & 2047;
  int co = (o >> 11) & 127;
  int tap = o >> 18;
  Whg[o] = (_Float16)saw1[((size_t)co * 2048 + ci) * 9 + tap];
}

// ---------------- in_proj ----------------
__global__ void __launch_bounds__(512) k_inproj(const float* __restrict__ x,
                                                const float* __restrict__ inWT,
                                                float* __restrict__ xz) {
  int d = threadIdx.x;
  int b = blockIdx.y;
  int p0 = blockIdx.x * 8;
  const float* xb = x + (size_t)(b * 256) * 1024 + p0;
  float acc[8];
#pragma unroll
  for (int j = 0; j < 8; ++j) acc[j] = 0.f;
  for (int c = 0; c < 256; ++c) {
    float w = inWT[c * 512 + d];
    const float* xr = xb + c * 1024;
    float4 a  = *(const float4*)xr;
    float4 b4 = *(const float4*)(xr + 4);
    acc[0] = fmaf(w, a.x,  acc[0]); acc[1] = fmaf(w, a.y,  acc[1]);
    acc[2] = fmaf(w, a.z,  acc[2]); acc[3] = fmaf(w, a.w,  acc[3]);
    acc[4] = fmaf(w, b4.x, acc[4]); acc[5] = fmaf(w, b4.y, acc[5]);
    acc[6] = fmaf(w, b4.z, acc[6]); acc[7] = fmaf(w, b4.w, acc[7]);
  }
  float* o = xz + (size_t)(b * 512 + d) * 1024 + p0;
  float4 o0 = {acc[0], acc[1], acc[2], acc[3]};
  float4 o1 = {acc[4], acc[5], acc[6], acc[7]};
  *(float4*)o = o0; *(float4*)(o + 4) = o1;
}

// ---------------- depthwise conv1d + SiLU (x-half) ----------------
__global__ void k_convx(const float* __restrict__ xz, const float* __restrict__ cw,
                        const float* __restrict__ cb, float* __restrict__ xseq) {
  int l  = blockIdx.x * 256 + threadIdx.x;
  int rd = blockIdx.y; int r = rd >> 8; int d = rd & 255;
  int b  = blockIdx.z;
  float w0 = cw[rd*4+0], w1 = cw[rd*4+1], w2 = cw[rd*4+2], w3 = cw[rd*4+3];
  float acc = cb[rd];
  const float* src = xz + (size_t)(b * 512 + d) * 1024;
  if (l - 1 >= 0)   acc = fmaf(w0, src[srcmap(r, l - 1)], acc);
  acc = fmaf(w1, src[srcmap(r, l)], acc);
  if (l + 1 < 1024) acc = fmaf(w2, src[srcmap(r, l + 1)], acc);
  if (l + 2 < 1024) acc = fmaf(w3, src[srcmap(r, l + 2)], acc);
  xseq[((size_t)(b * 4 + r) * 256 + d) * 1024 + l] = siluf(acc);
}

// z-half -> un-rotated into Y channels [256..512)
__global__ void k_convz(const float* __restrict__ xz, const float* __restrict__ cw,
                        const float* __restrict__ cb, float* __restrict__ Y) {
  int l  = blockIdx.x * 256 + threadIdx.x;
  int rd = blockIdx.y; int r = rd >> 8; int d = rd & 255;
  int b  = blockIdx.z;
  float w0 = cw[rd*4+0], w1 = cw[rd*4+1], w2 = cw[rd*4+2], w3 = cw[rd*4+3];
  float acc = cb[rd];
  const float* src = xz + (size_t)(b * 512 + 256 + d) * 1024;
  if (l - 1 >= 0)   acc = fmaf(w0, src[srcmap(r, l - 1)], acc);
  acc = fmaf(w1, src[srcmap(r, l)], acc);
  if (l + 1 < 1024) acc = fmaf(w2, src[srcmap(r, l + 1)], acc);
  if (l + 2 < 1024) acc = fmaf(w3, src[srcmap(r, l + 2)], acc);
  Y[((size_t)(b * 4 + r) * 512 + 256 + d) * 1024 + srcmap(r, l)] = siluf(acc);
}

// ---------------- x_dbl ----------------
__global__ void k_xdbl(const float* __restrict__ xseq, const float* __restrict__ xpw,
                       float* __restrict__ xdbl) {
  int l  = blockIdx.x * 256 + threadIdx.x;
  int k  = blockIdx.y;
  int br = blockIdx.z;
  int r  = br & 3;
  const float* w  = xpw + (r * 48 + k) * 256;
  const float* xs = xseq + (size_t)(br * 256) * 1024 + l;
  float acc = 0.f;
  for (int d = 0; d < 256; ++d) acc = fmaf(w[d], xs[(size_t)d * 1024], acc);
  xdbl[((size_t)br * 48 + k) * 1024 + l] = acc;
}

// ---------------- chunked selective scan ----------------
// Pass A: per chunk (64 steps), h0=0 -> chunk-end state hcar + per-state a-product
__global__ void __launch_bounds__(256) k_scanA(
    const float* __restrict__ xseq, const float* __restrict__ xdbl,
    const float* __restrict__ dtw_, const float* __restrict__ dtb_,
    const float* __restrict__ alogs,
    float* __restrict__ aprodg, float* __restrict__ hcarg) {
  int ch = blockIdx.x;            // 0..15
  int br = blockIdx.y; int r = br & 3;
  int d  = threadIdx.x;
  int rd = r * 256 + d;
  float dtw[16], A[16], h[16], ap[16];
#pragma unroll
  for (int k = 0; k < 16; ++k) dtw[k] = dtw_[rd * 16 + k];
#pragma unroll
  for (int n = 0; n < 16; ++n) A[n] = -__expf(alogs[rd * 16 + n]);
#pragma unroll
  for (int n = 0; n < 16; ++n) { h[n] = 0.f; ap[n] = 1.f; }
  float bias = dtb_[rd];
  __shared__ float tile[48][64];
  int l0 = ch * 64;
  const float* xd = xdbl + (size_t)(br * 48) * 1024 + l0;
  const float* us = xseq + (size_t)(br * 256 + d) * 1024 + l0;
  for (int idx = threadIdx.x; idx < 48 * 64; idx += 256) {
    int k = idx >> 6, c = idx & 63;
    tile[k][c] = xd[(size_t)k * 1024 + c];
  }
  __syncthreads();
  for (int c4 = 0; c4 < 16; ++c4) {
    float4 uv = *(const float4*)(us + c4 * 4);
    float uarr[4] = {uv.x, uv.y, uv.z, uv.w};
#pragma unroll
    for (int cc = 0; cc < 4; ++cc) {
      int c = c4 * 4 + cc;
      float u = uarr[cc];
      float delta = bias;
#pragma unroll
      for (int k = 0; k < 16; ++k) delta = fmaf(tile[k][c], dtw[k], delta);
      float sp = (delta > 20.f) ? delta : log1pf(__expf(delta));
      float du = sp * u;
#pragma unroll
      for (int n = 0; n < 16; ++n) {
        float e = __expf(sp * A[n]);
        h[n]  = fmaf(e, h[n], du * tile[16 + n][c]);
        ap[n] *= e;
      }
    }
  }
  float* apo = aprodg + (((size_t)br * 16 + ch) * 256 + d) * 16;
  float* hco = hcarg  + (((size_t)br * 16 + ch) * 256 + d) * 16;
#pragma unroll
  for (int n = 0; n < 16; ++n) { apo[n] = ap[n]; hco[n] = h[n]; }
}

// Pass B: sequential prefix over 16 chunks; converts hcar (chunk-end, h0=0)
// into chunk-INCOMING states, in place.
__global__ void k_scanB(const float* __restrict__ aprodg, float* __restrict__ hcarg) {
  int t  = blockIdx.x * 256 + threadIdx.x;   // 0..131071 = br*4096 + d*16 + n
  int br = t >> 12;
  int dn = t & 4095;
  size_t base = (size_t)br * 16 * 4096 + dn;
  float h = 0.f;
  for (int c = 0; c < 16; ++c) {
    size_t o = base + (size_t)c * 4096;
    float hin = h;
    h = fmaf(aprodg[o], h, hcarg[o]);
    hcarg[o] = hin;
  }
}

// Pass C: re-run chunk with true incoming state, emit y (un-rotated scatter into Y)
__global__ void __launch_bounds__(256) k_scanC(
    const float* __restrict__ xseq, const float* __restrict__ xdbl,
    const float* __restrict__ dtw_, const float* __restrict__ dtb_,
    const float* __restrict__ alogs, const float* __restrict__ ds_,
    const float* __restrict__ hcarg, float* __restrict__ Y) {
  int ch = blockIdx.x;
  int br = blockIdx.y; int r = br & 3;
  int d  = threadIdx.x;
  int rd = r * 256 + d;
  float dtw[16], A[16], h[16];
#pragma unroll
  for (int k = 0; k < 16; ++k) dtw[k] = dtw_[rd * 16 + k];
#pragma unroll
  for (int n = 0; n < 16; ++n) A[n] = -__expf(alogs[rd * 16 + n]);
  const float* hc = hcarg + (((size_t)br * 16 + ch) * 256 + d) * 16;
#pragma unroll
  for (int n = 0; n < 16; ++n) h[n] = hc[n];
  float bias = dtb_[rd];
  float dsv  = ds_[rd];
  __shared__ float tile[48][64];
  int l0 = ch * 64;
  const float* xd = xdbl + (size_t)(br * 48) * 1024 + l0;
  const float* us = xseq + (size_t)(br * 256 + d) * 1024 + l0;
  float* yo = Y + (size_t)(br * 512 + d) * 1024;
  for (int idx = threadIdx.x; idx < 48 * 64; idx += 256) {
    int k = idx >> 6, c = idx & 63;
    tile[k][c] = xd[(size_t)k * 1024 + c];
  }
  __syncthreads();
  for (int c4 = 0; c4 < 16; ++c4) {
    float4 uv = *(const float4*)(us + c4 * 4);
    float uarr[4] = {uv.x, uv.y, uv.z, uv.w};
#pragma unroll
    for (int cc = 0; cc < 4; ++cc) {
      int c = c4 * 4 + cc;
      float u = uarr[cc];
      float delta = bias;
#pragma unroll
      for (int k = 0; k < 16; ++k) delta = fmaf(tile[k][c], dtw[k], delta);
      float sp = (delta > 20.f) ? delta : log1pf(__expf(delta));
      float du = sp * u;
      float acc = 0.f;
#pragma unroll
      for (int n = 0; n < 16; ++n) {
        float e = __expf(sp * A[n]);
        h[n] = fmaf(e, h[n], du * tile[16 + n][c]);
        acc  = fmaf(h[n], tile[32 + n][c], acc);
      }
      yo[srcmap(r, l0 + c)] = fmaf(dsv, u, acc);
    }
  }
}

// ---------------- Y -> fp16 transposed Ytg[b][pix][ci] ----------------
__global__ void k_ytr(const float* __restrict__ Y, _Float16* __restrict__ Ytg) {
  __shared__ float t[32][132];
  int p0  = blockIdx.x * 128;
  int ci0 = blockIdx.y * 32;
  int b   = blockIdx.z;
  const float* src = Y + ((size_t)(b * 2048 + ci0)) * 1024 + p0;
#pragma unroll
  for (int i = 0; i < 16; ++i) {
    int idx = threadIdx.x + i * 256;
    int ci = idx >> 7, pp = idx & 127;
    t[ci][pp] = src[(size_t)ci * 1024 + pp];
  }
  __syncthreads();
  int pp = threadIdx.x >> 1;
  int ch = (threadIdx.x & 1) * 16;
  _Float16 buf[16];
#pragma unroll
  for (int j = 0; j < 16; ++j) buf[j] = (_Float16)t[ch + j][pp];
  _Float16* dst = Ytg + ((size_t)(b * 1024) + p0 + pp) * 2048 + ci0 + ch;
  *(float4*)dst = *(const float4*)buf;
  *(float4*)(dst + 8) = *(const float4*)(buf + 8);
}

// ---------------- spatial-attn conv1 via MFMA (implicit GEMM, split-K=4) ----------------
__global__ void __launch_bounds__(128) k_samfma(const _Float16* __restrict__ Ytg,
                                                const _Float16* __restrict__ Whg,
                                                float* __restrict__ cpart) {
  int wid = threadIdx.x >> 6, lane = threadIdx.x & 63;
  int r = lane & 15, g = lane >> 4;
  int mblk = blockIdx.x;
  int b = mblk >> 3;
  int rowbase = (mblk & 7) * 4 + wid * 2;
  int n0 = blockIdx.y * 64;
  int k0 = blockIdx.z * 512;
  const _Float16* Yb = Ytg + (size_t)b * (1024 * 2048);
  f4 acc[4][4];
#pragma unroll
  for (int mi = 0; mi < 4; ++mi)
#pragma unroll
    for (int ni = 0; ni < 4; ++ni) acc[mi][ni] = (f4){0.f, 0.f, 0.f, 0.f};
  const half8 zero8 = {0, 0, 0, 0, 0, 0, 0, 0};

  for (int kc = 0; kc < 16; ++kc) {
    int ci = k0 + kc * 32 + g * 8;
#pragma unroll
    for (int tap = 0; tap < 9; ++tap) {
      const int dh = tap / 3 - 1, dw = tap % 3 - 1;
      half8 av[4], bv[4];
#pragma unroll
      for (int mi = 0; mi < 4; ++mi) {
        int pr = rowbase + ((mi * 16 + r) >> 5) + dh;
        int pc = ((mi * 16 + r) & 31) + dw;
        bool ok = ((unsigned)pr < 32u) && ((unsigned)pc < 32u);
        const _Float16* ap = Yb + (size_t)((ok ? pr : 0) * 32 + (ok ? pc : 0)) * 2048 + ci;
        half8 v = *(const half8*)ap;
        av[mi] = ok ? v : zero8;
      }
#pragma unroll
      for (int ni = 0; ni < 4; ++ni) {
        int co = n0 + ni * 16 + r;
        bv[ni] = *(const half8*)(Whg + (size_t)(tap * 128 + co) * 2048 + ci);
      }
#pragma unroll
      for (int mi = 0; mi < 4; ++mi)
#pragma unroll
        for (int ni = 0; ni < 4; ++ni)
          acc[mi][ni] = __builtin_amdgcn_mfma_f32_16x16x32_f16(av[mi], bv[ni], acc[mi][ni], 0, 0, 0);
    }
  }
  float* cp = cpart + (size_t)blockIdx.z * (8192 * 128);
  int basepix = b * 1024 + rowbase * 32;
#pragma unroll
  for (int mi = 0; mi < 4; ++mi)
#pragma unroll
    for (int ni = 0; ni < 4; ++ni) {
      int co = n0 + ni * 16 + r;
#pragma unroll
      for (int j = 0; j < 4; ++j)
        cp[(size_t)(basepix + mi * 16 + g * 4 + j) * 128 + co] = acc[mi][ni][j];
    }
}

// ---------------- reduce partials + bias + relu + conv2 + softmax ----------------
__global__ void k_saconv2f(const float* __restrict__ cpart, const float* __restrict__ sab1,
                           const float* __restrict__ saw2, const float* __restrict__ sab2,
                           float* __restrict__ swout) {
  int p = blockIdx.x * 256 + threadIdx.x;
  int b = blockIdx.y;
  int pix = b * 1024 + p;
  const float* c0 = cpart + (size_t)pix * 128;
  float a0 = sab2[0], a1 = sab2[1], a2 = sab2[2], a3 = sab2[3];
  for (int ci = 0; ci < 128; ++ci) {
    float s = c0[ci] + c0[ci + 1048576] + c0[ci + 2097152] + c0[ci + 3145728];
    float v = fmaxf(s + sab1[ci], 0.f);
    a0 = fmaf(v, saw2[ci],       a0);
    a1 = fmaf(v, saw2[128 + ci], a1);
    a2 = fmaf(v, saw2[256 + ci], a2);
    a3 = fmaf(v, saw2[384 + ci], a3);
  }
  float m = fmaxf(fmaxf(a0, a1), fmaxf(a2, a3));
  float e0 = __expf(a0 - m), e1 = __expf(a1 - m), e2 = __expf(a2 - m), e3 = __expf(a3 - m);
  float inv = 1.f / (e0 + e1 + e2 + e3);
  swout[(b * 4 + 0) * 1024 + p] = e0 * inv;
  swout[(b * 4 + 1) * 1024 + p] = e1 * inv;
  swout[(b * 4 + 2) * 1024 + p] = e2 * inv;
  swout[(b * 4 + 3) * 1024 + p] = e3 * inv;
}

// ---------------- channel avg ----------------
__global__ void k_cavg(const float* __restrict__ Y, float* __restrict__ cavg) {
  int gid = blockIdx.x * 256 + threadIdx.x;
  const float4* yr = (const float4*)(Y + (size_t)gid * 1024);
  float s = 0.f;
  for (int i = 0; i < 256; ++i) {
    float4 v = yr[i];
    s += v.x + v.y + v.z + v.w;
  }
  cavg[gid] = s * (1.f / 1024.f);
}

// ---------------- channel attention ----------------
__global__ void k_cw(const float* __restrict__ cavg, const float* __restrict__ caw1,
                     const float* __restrict__ caw2, float* __restrict__ cwout) {
  int b = blockIdx.x;
  int t = threadIdx.x;
  __shared__ float hid[32];
  __shared__ float vv[4];
  if (t < 32) {
    float a = 0.f;
    const float* cv = cavg + b * 2048;
    const float* wr = caw1 + t * 2048;
    for (int i = 0; i < 2048; ++i) a = fmaf(wr[i], cv[i], a);
    hid[t] = fmaxf(a, 0.f);
  }
  __syncthreads();
  if (t < 4) {
    float a = 0.f;
    for (int i = 0; i < 32; ++i) a = fmaf(caw2[t * 32 + i], hid[i], a);
    vv[t] = a;
  }
  __syncthreads();
  if (t < 4) {
    float m = fmaxf(fmaxf(vv[0], vv[1]), fmaxf(vv[2], vv[3]));
    float e = __expf(vv[t] - m);
    float s = __expf(vv[0] - m) + __expf(vv[1] - m) + __expf(vv[2] - m) + __expf(vv[3] - m);
    cwout[b * 4 + t] = e / s;
  }
}

// ---------------- spatial & channel mixes ----------------
__global__ void k_spatialchannel(const float* __restrict__ Y, const float* __restrict__ swv,
                                 const float* __restrict__ cwv, float* __restrict__ spatial,
                                 float* __restrict__ channel) {
  int idx = blockIdx.x * 256 + threadIdx.x;
  int pq = idx & 255;
  int c  = (idx >> 8) & 511;
  int b  = idx >> 17;
  int p  = pq * 4;
  float sx=0,sy=0,sz=0,sw_=0, cx=0,cy=0,cz=0,cw_=0;
#pragma unroll
  for (int r = 0; r < 4; ++r) {
    float4 y = *(const float4*)(Y + ((size_t)(b * 4 + r) * 512 + c) * 1024 + p);
    float4 s = *(const float4*)(swv + (size_t)(b * 4 + r) * 1024 + p);
    float cr = cwv[b * 4 + r];
    sx = fmaf(y.x, s.x, sx); sy = fmaf(y.y, s.y, sy);
    sz = fmaf(y.z, s.z, sz); sw_ = fmaf(y.w, s.w, sw_);
    cx = fmaf(y.x, cr, cx); cy = fmaf(y.y, cr, cy);
    cz = fmaf(y.z, cr, cz); cw_ = fmaf(y.w, cr, cw_);
  }
  float4 so = {sx, sy, sz, sw_}, co = {cx, cy, cz, cw_};
  *(float4*)(spatial + ((size_t)(b * 512) + c) * 1024 + p) = so;
  *(float4*)(channel + ((size_t)(b * 512) + c) * 1024 + p) = co;
}

// ---------------- gate + fuse ----------------
__global__ void __launch_bounds__(512) k_gate(
    const float* __restrict__ spatial, const float* __restrict__ channel,
    const float* __restrict__ gwT, const float* __restrict__ gb,
    float* __restrict__ fused) {
  int c  = threadIdx.x;
  int b  = blockIdx.y;
  int p0 = blockIdx.x * 8;
  const float* sp = spatial + (size_t)(b * 512) * 1024 + p0;
  const float* ch = channel + (size_t)(b * 512) * 1024 + p0;
  float acc[8];
#pragma unroll
  for (int j = 0; j < 8; ++j) acc[j] = 0.f;
  for (int d = 0; d < 512; ++d) {
    float w = gwT[d * 512 + c];
    const float* a = sp + (size_t)d * 1024;
    float4 v0 = *(const float4*)a, v1 = *(const float4*)(a + 4);
    acc[0]=fmaf(w,v0.x,acc[0]); acc[1]=fmaf(w,v0.y,acc[1]);
    acc[2]=fmaf(w,v0.z,acc[2]); acc[3]=fmaf(w,v0.w,acc[3]);
    acc[4]=fmaf(w,v1.x,acc[4]); acc[5]=fmaf(w,v1.y,acc[5]);
    acc[6]=fmaf(w,v1.z,acc[6]); acc[7]=fmaf(w,v1.w,acc[7]);
  }
  for (int d = 0; d < 512; ++d) {
    float w = gwT[(512 + d) * 512 + c];
    const float* a = ch + (size_t)d * 1024;
    float4 v0 = *(const float4*)a, v1 = *(const float4*)(a + 4);
    acc[0]=fmaf(w,v0.x,acc[0]); acc[1]=fmaf(w,v0.y,acc[1]);
    acc[2]=fmaf(w,v0.z,acc[2]); acc[3]=fmaf(w,v0.w,acc[3]);
    acc[4]=fmaf(w,v1.x,acc[4]); acc[5]=fmaf(w,v1.y,acc[5]);
    acc[6]=fmaf(w,v1.z,acc[6]); acc[7]=fmaf(w,v1.w,acc[7]);
  }
  float bias = gb[c];
  const float* spc = sp + (size_t)c * 1024;
  const float* chc = ch + (size_t)c * 1024;
  float* fo = fused + ((size_t)(b * 512) + c) * 1024 + p0;
#pragma unroll
  for (int j = 0; j < 8; ++j) {
    float g = sigmoidf_(acc[j] + bias);
    fo[j] = g * spc[j] + (1.f - g) * chc[j];
  }
}

// ---------------- out_proj + GELU ----------------
__global__ void k_outproj(const float* __restrict__ fused, const float* __restrict__ opWT,
                          float* __restrict__ out) {
  int co = threadIdx.x;
  int b  = blockIdx.y;
  int p0 = blockIdx.x * 8;
  const float* fb = fused + (size_t)(b * 512) * 1024 + p0;
  float acc[8];
#pragma unroll
  for (int j = 0; j < 8; ++j) acc[j] = 0.f;
  for (int d = 0; d < 512; ++d) {
    float w = opWT[d * 256 + co];
    const float* a = fb + (size_t)d * 1024;
    float4 v0 = *(const float4*)a, v1 = *(const float4*)(a + 4);
    acc[0]=fmaf(w,v0.x,acc[0]); acc[1]=fmaf(w,v0.y,acc[1]);
    acc[2]=fmaf(w,v0.z,acc[2]); acc[3]=fmaf(w,v0.w,acc[3]);
    acc[4]=fmaf(w,v1.x,acc[4]); acc[5]=fmaf(w,v1.y,acc[5]);
    acc[6]=fmaf(w,v1.z,acc[6]); acc[7]=fmaf(w,v1.w,acc[7]);
  }
  float* o = out + ((size_t)(b * 256) + co) * 1024 + p0;
#pragma unroll
  for (int j = 0; j < 8; ++j) o[j] = geluf(acc[j]);
}

extern "C" void kernel_launch(void* const* d_in, const int* in_sizes, int n_in,
                              void* d_out, int out_size, void* d_ws, size_t ws_size,
                              hipStream_t stream) {
  const float* x    = (const float*)d_in[0];
  const float* inw  = (const float*)d_in[1];
  const float* opw  = (const float*)d_in[2];
  const float* cxw  = (const float*)d_in[3];
  const float* cxb  = (const float*)d_in[4];
  const float* czw  = (const float*)d_in[5];
  const float* czb  = (const float*)d_in[6];
  const float* xpw  = (const float*)d_in[7];
  const float* dtw  = (const float*)d_in[8];
  const float* dtb  = (const float*)d_in[9];
  const float* alog = (const float*)d_in[10];
  const float* ds   = (const float*)d_in[11];
  const float* saw1 = (const float*)d_in[12];
  const float* sab1 = (const float*)d_in[13];
  const float* saw2 = (const float*)d_in[14];
  const float* sab2 = (const float*)d_in[15];
  const float* caw1 = (const float*)d_in[16];
  const float* caw2 = (const float*)d_in[17];
  const float* gw   = (const float*)d_in[18];
  const float* gb   = (const float*)d_in[19];

  float* ws = (float*)d_ws;
  // workspace layout (floats); total = 33,996,832 floats = 136.0 MB
  float* xz   = ws + 0;          //  4,194,304  [alias: scan carries -> Cpart -> fused]
  float* xseq = ws + 4194304;    //  8,388,608  [alias: Ytg fp16, then spatial|channel]
  float* xdbl = ws + 12582912;   //  1,572,864
  float* Y    = ws + 14155776;   // 16,777,216
  float* sa1  = ws + 30932992;   //  1,048,576  (unused)
  float* swb  = ws + 31981568;   //     32,768
  float* cavg = ws + 32014336;   //     16,384
  float* cwb  = ws + 32030720;   //         32
  float* inWT = ws + 32030752;   //    131,072
  float* opWT = ws + 32161824;   //    131,072
  float* gwT  = ws + 32292896;   //    524,288
  float* WhgF = ws + 32817184;   //  1,179,648  (Whg fp16: 2,359,296 halves)
  (void)sa1;
  // scan carries: 2 x (32br x 16chunk x 256d x 16n) = 4,194,304 floats, in dead xz region
  float* aprodg = xz;            //  2,097,152
  float* hcarg  = xz + 2097152;  //  2,097,152
  float* Cpart = xz;
  _Float16* Ytg = (_Float16*)xseq;
  _Float16* Whg = (_Float16*)WhgF;
  float* spatial = xseq;
  float* channel = xseq + 4194304;
  float* fused   = xz;

  k_prep<<<3072, 256, 0, stream>>>(inw, opw, gw, inWT, opWT, gwT);
  k_wprep<<<9216, 256, 0, stream>>>(saw1, Whg);
  k_inproj<<<dim3(128, 8), 512, 0, stream>>>(x, inWT, xz);
  k_convx<<<dim3(4, 1024, 8), 256, 0, stream>>>(xz, cxw, cxb, xseq);
  k_convz<<<dim3(4, 1024, 8), 256, 0, stream>>>(xz, czw, czb, Y);
  k_xdbl<<<dim3(4, 48, 32), 256, 0, stream>>>(xseq, xpw, xdbl);
  k_scanA<<<dim3(16, 32), 256, 0, stream>>>(xseq, xdbl, dtw, dtb, alog, aprodg, hcarg);
  k_scanB<<<512, 256, 0, stream>>>(aprodg, hcarg);
  k_scanC<<<dim3(16, 32), 256, 0, stream>>>(xseq, xdbl, dtw, dtb, alog, ds, hcarg, Y);
  k_ytr<<<dim3(8, 64, 8), 256, 0, stream>>>(Y, Ytg);
  k_samfma<<<dim3(64, 2, 4), 128, 0, stream>>>(Ytg, Whg, Cpart);
  k_saconv2f<<<dim3(4, 8), 256, 0, stream>>>(Cpart, sab1, saw2, sab2, swb);
  k_cavg<<<64, 256, 0, stream>>>(Y, cavg);
  k_cw<<<8, 64, 0, stream>>>(cavg, caw1, caw2, cwb);
  k_spatialchannel<<<4096, 256, 0, stream>>>(Y, swb, cwb, spatial, channel);
  k_gate<<<dim3(128, 8), 512, 0, stream>>>(spatial, channel, gwT, gb, fused);
  k_outproj<<<dim3(128, 8), 256, 0, stream>>>(fused, opWT, (float*)d_out);
}

// Round 4
// 718.640 us; speedup vs baseline: 5.4734x; 1.2498x over previous
//
#include <hip/hip_runtime.h>
#include <math.h>

// dims: B=8, DM=256, H=W=32, L=HW=1024, R=4, DI=512, DH=256, N=16, K=4, DTR=16

typedef _Float16 half8 __attribute__((ext_vector_type(8)));
typedef float f4 __attribute__((ext_vector_type(4)));

__device__ __forceinline__ int srcmap(int r, int l) {
  int i = l >> 5, j = l & 31;
  int h, w;
  if (r == 0)      { h = i;      w = j;      }
  else if (r == 1) { h = j;      w = 31 - i; }
  else if (r == 2) { h = 31 - i; w = 31 - j; }
  else             { h = 31 - j; w = i;      }
  return (h << 5) + w;
}

__device__ __forceinline__ float siluf(float x)    { return x / (1.f + __expf(-x)); }
__device__ __forceinline__ float sigmoidf_(float x){ return 1.f / (1.f + __expf(-x)); }
__device__ __forceinline__ float geluf(float x) {
  float x3 = x * x * x;
  return 0.5f * x * (1.f + tanhf(0.7978845608028654f * (x + 0.044715f * x3)));
}

// ---------------- prep: inWT fp32 transpose; gwH/opH fp16 casts (native layout) ----------------
__global__ void k_prep(const float* __restrict__ inw, const float* __restrict__ gw,
                       const float* __restrict__ opw,
                       float* __restrict__ inWT, _Float16* __restrict__ gwH,
                       _Float16* __restrict__ opH) {
  int idx = blockIdx.x * 256 + threadIdx.x;
  if (idx < 131072) {
    int c = idx >> 9, d = idx & 511;
    inWT[idx] = inw[d * 256 + c];
  } else if (idx < 655360) {
    int i = idx - 131072;            // 524288 = 512c x 1024k
    gwH[i] = (_Float16)gw[i];
  } else {
    int i = idx - 655360;            // 131072 = 256co x 512k
    opH[i] = (_Float16)opw[i];
  }
}

// ---------------- fp16 pack of sa_w1: Whg[tap][co][ci] ----------------
__global__ void k_wprep(const float* __restrict__ saw1, _Float16* __restrict__ Whg) {
  int o = blockIdx.x * 256 + threadIdx.x;           // < 2,359,296
  int ci = o & 2047;
  int co = (o >> 11) & 127;
  int tap = o >> 18;
  Whg[o] = (_Float16)saw1[((size_t)co * 2048 + ci) * 9 + tap];
}

// ---------------- in_proj ----------------
__global__ void __launch_bounds__(512) k_inproj(const float* __restrict__ x,
                                                const float* __restrict__ inWT,
                                                float* __restrict__ xz) {
  int d = threadIdx.x;
  int b = blockIdx.y;
  int p0 = blockIdx.x * 8;
  const float* xb = x + (size_t)(b * 256) * 1024 + p0;
  float acc[8];
#pragma unroll
  for (int j = 0; j < 8; ++j) acc[j] = 0.f;
  for (int c = 0; c < 256; ++c) {
    float w = inWT[c * 512 + d];
    const float* xr = xb + c * 1024;
    float4 a  = *(const float4*)xr;
    float4 b4 = *(const float4*)(xr + 4);
    acc[0] = fmaf(w, a.x,  acc[0]); acc[1] = fmaf(w, a.y,  acc[1]);
    acc[2] = fmaf(w, a.z,  acc[2]); acc[3] = fmaf(w, a.w,  acc[3]);
    acc[4] = fmaf(w, b4.x, acc[4]); acc[5] = fmaf(w, b4.y, acc[5]);
    acc[6] = fmaf(w, b4.z, acc[6]); acc[7] = fmaf(w, b4.w, acc[7]);
  }
  float* o = xz + (size_t)(b * 512 + d) * 1024 + p0;
  float4 o0 = {acc[0], acc[1], acc[2], acc[3]};
  float4 o1 = {acc[4], acc[5], acc[6], acc[7]};
  *(float4*)o = o0; *(float4*)(o + 4) = o1;
}

// ---------------- depthwise conv1d + SiLU (x-half) ----------------
__global__ void k_convx(const float* __restrict__ xz, const float* __restrict__ cw,
                        const float* __restrict__ cb, float* __restrict__ xseq) {
  int l  = blockIdx.x * 256 + threadIdx.x;
  int rd = blockIdx.y; int r = rd >> 8; int d = rd & 255;
  int b  = blockIdx.z;
  float w0 = cw[rd*4+0], w1 = cw[rd*4+1], w2 = cw[rd*4+2], w3 = cw[rd*4+3];
  float acc = cb[rd];
  const float* src = xz + (size_t)(b * 512 + d) * 1024;
  if (l - 1 >= 0)   acc = fmaf(w0, src[srcmap(r, l - 1)], acc);
  acc = fmaf(w1, src[srcmap(r, l)], acc);
  if (l + 1 < 1024) acc = fmaf(w2, src[srcmap(r, l + 1)], acc);
  if (l + 2 < 1024) acc = fmaf(w3, src[srcmap(r, l + 2)], acc);
  xseq[((size_t)(b * 4 + r) * 256 + d) * 1024 + l] = siluf(acc);
}

// z-half -> un-rotated into Y channels [256..512)
__global__ void k_convz(const float* __restrict__ xz, const float* __restrict__ cw,
                        const float* __restrict__ cb, float* __restrict__ Y) {
  int l  = blockIdx.x * 256 + threadIdx.x;
  int rd = blockIdx.y; int r = rd >> 8; int d = rd & 255;
  int b  = blockIdx.z;
  float w0 = cw[rd*4+0], w1 = cw[rd*4+1], w2 = cw[rd*4+2], w3 = cw[rd*4+3];
  float acc = cb[rd];
  const float* src = xz + (size_t)(b * 512 + 256 + d) * 1024;
  if (l - 1 >= 0)   acc = fmaf(w0, src[srcmap(r, l - 1)], acc);
  acc = fmaf(w1, src[srcmap(r, l)], acc);
  if (l + 1 < 1024) acc = fmaf(w2, src[srcmap(r, l + 1)], acc);
  if (l + 2 < 1024) acc = fmaf(w3, src[srcmap(r, l + 2)], acc);
  Y[((size_t)(b * 4 + r) * 512 + 256 + d) * 1024 + srcmap(r, l)] = siluf(acc);
}

// ---------------- x_dbl ----------------
__global__ void k_xdbl(const float* __restrict__ xseq, const float* __restrict__ xpw,
                       float* __restrict__ xdbl) {
  int l  = blockIdx.x * 256 + threadIdx.x;
  int k  = blockIdx.y;
  int br = blockIdx.z;
  int r  = br & 3;
  const float* w  = xpw + (r * 48 + k) * 256;
  const float* xs = xseq + (size_t)(br * 256) * 1024 + l;
  float acc = 0.f;
  for (int d = 0; d < 256; ++d) acc = fmaf(w[d], xs[(size_t)d * 1024], acc);
  xdbl[((size_t)br * 48 + k) * 1024 + l] = acc;
}

// ---------------- chunked selective scan ----------------
__global__ void __launch_bounds__(256) k_scanA(
    const float* __restrict__ xseq, const float* __restrict__ xdbl,
    const float* __restrict__ dtw_, const float* __restrict__ dtb_,
    const float* __restrict__ alogs,
    float* __restrict__ aprodg, float* __restrict__ hcarg) {
  int ch = blockIdx.x;
  int br = blockIdx.y; int r = br & 3;
  int d  = threadIdx.x;
  int rd = r * 256 + d;
  float dtw[16], A[16], h[16], ap[16];
#pragma unroll
  for (int k = 0; k < 16; ++k) dtw[k] = dtw_[rd * 16 + k];
#pragma unroll
  for (int n = 0; n < 16; ++n) A[n] = -__expf(alogs[rd * 16 + n]);
#pragma unroll
  for (int n = 0; n < 16; ++n) { h[n] = 0.f; ap[n] = 1.f; }
  float bias = dtb_[rd];
  __shared__ float tile[48][64];
  int l0 = ch * 64;
  const float* xd = xdbl + (size_t)(br * 48) * 1024 + l0;
  const float* us = xseq + (size_t)(br * 256 + d) * 1024 + l0;
  for (int idx = threadIdx.x; idx < 48 * 64; idx += 256) {
    int k = idx >> 6, c = idx & 63;
    tile[k][c] = xd[(size_t)k * 1024 + c];
  }
  __syncthreads();
  for (int c4 = 0; c4 < 16; ++c4) {
    float4 uv = *(const float4*)(us + c4 * 4);
    float uarr[4] = {uv.x, uv.y, uv.z, uv.w};
#pragma unroll
    for (int cc = 0; cc < 4; ++cc) {
      int c = c4 * 4 + cc;
      float u = uarr[cc];
      float delta = bias;
#pragma unroll
      for (int k = 0; k < 16; ++k) delta = fmaf(tile[k][c], dtw[k], delta);
      float sp = (delta > 20.f) ? delta : log1pf(__expf(delta));
      float du = sp * u;
#pragma unroll
      for (int n = 0; n < 16; ++n) {
        float e = __expf(sp * A[n]);
        h[n]  = fmaf(e, h[n], du * tile[16 + n][c]);
        ap[n] *= e;
      }
    }
  }
  float* apo = aprodg + (((size_t)br * 16 + ch) * 256 + d) * 16;
  float* hco = hcarg  + (((size_t)br * 16 + ch) * 256 + d) * 16;
#pragma unroll
  for (int n = 0; n < 16; ++n) { apo[n] = ap[n]; hco[n] = h[n]; }
}

__global__ void k_scanB(const float* __restrict__ aprodg, float* __restrict__ hcarg) {
  int t  = blockIdx.x * 256 + threadIdx.x;
  int br = t >> 12;
  int dn = t & 4095;
  size_t base = (size_t)br * 16 * 4096 + dn;
  float h = 0.f;
  for (int c = 0; c < 16; ++c) {
    size_t o = base + (size_t)c * 4096;
    float hin = h;
    h = fmaf(aprodg[o], h, hcarg[o]);
    hcarg[o] = hin;
  }
}

__global__ void __launch_bounds__(256) k_scanC(
    const float* __restrict__ xseq, const float* __restrict__ xdbl,
    const float* __restrict__ dtw_, const float* __restrict__ dtb_,
    const float* __restrict__ alogs, const float* __restrict__ ds_,
    const float* __restrict__ hcarg, float* __restrict__ Y) {
  int ch = blockIdx.x;
  int br = blockIdx.y; int r = br & 3;
  int d  = threadIdx.x;
  int rd = r * 256 + d;
  float dtw[16], A[16], h[16];
#pragma unroll
  for (int k = 0; k < 16; ++k) dtw[k] = dtw_[rd * 16 + k];
#pragma unroll
  for (int n = 0; n < 16; ++n) A[n] = -__expf(alogs[rd * 16 + n]);
  const float* hc = hcarg + (((size_t)br * 16 + ch) * 256 + d) * 16;
#pragma unroll
  for (int n = 0; n < 16; ++n) h[n] = hc[n];
  float bias = dtb_[rd];
  float dsv  = ds_[rd];
  __shared__ float tile[48][64];
  int l0 = ch * 64;
  const float* xd = xdbl + (size_t)(br * 48) * 1024 + l0;
  const float* us = xseq + (size_t)(br * 256 + d) * 1024 + l0;
  float* yo = Y + (size_t)(br * 512 + d) * 1024;
  for (int idx = threadIdx.x; idx < 48 * 64; idx += 256) {
    int k = idx >> 6, c = idx & 63;
    tile[k][c] = xd[(size_t)k * 1024 + c];
  }
  __syncthreads();
  for (int c4 = 0; c4 < 16; ++c4) {
    float4 uv = *(const float4*)(us + c4 * 4);
    float uarr[4] = {uv.x, uv.y, uv.z, uv.w};
#pragma unroll
    for (int cc = 0; cc < 4; ++cc) {
      int c = c4 * 4 + cc;
      float u = uarr[cc];
      float delta = bias;
#pragma unroll
      for (int k = 0; k < 16; ++k) delta = fmaf(tile[k][c], dtw[k], delta);
      float sp = (delta > 20.f) ? delta : log1pf(__expf(delta));
      float du = sp * u;
      float acc = 0.f;
#pragma unroll
      for (int n = 0; n < 16; ++n) {
        float e = __expf(sp * A[n]);
        h[n] = fmaf(e, h[n], du * tile[16 + n][c]);
        acc  = fmaf(h[n], tile[32 + n][c], acc);
      }
      yo[srcmap(r, l0 + c)] = fmaf(dsv, u, acc);
    }
  }
}

// ---------------- Y -> fp16 transposed Ytg[b][pix][ci] ----------------
__global__ void k_ytr(const float* __restrict__ Y, _Float16* __restrict__ Ytg) {
  __shared__ float t[32][132];
  int p0  = blockIdx.x * 128;
  int ci0 = blockIdx.y * 32;
  int b   = blockIdx.z;
  const float* src = Y + ((size_t)(b * 2048 + ci0)) * 1024 + p0;
#pragma unroll
  for (int i = 0; i < 16; ++i) {
    int idx = threadIdx.x + i * 256;
    int ci = idx >> 7, pp = idx & 127;
    t[ci][pp] = src[(size_t)ci * 1024 + pp];
  }
  __syncthreads();
  int pp = threadIdx.x >> 1;
  int ch = (threadIdx.x & 1) * 16;
  _Float16 buf[16];
#pragma unroll
  for (int j = 0; j < 16; ++j) buf[j] = (_Float16)t[ch + j][pp];
  _Float16* dst = Ytg + ((size_t)(b * 1024) + p0 + pp) * 2048 + ci0 + ch;
  *(float4*)dst = *(const float4*)buf;
  *(float4*)(dst + 8) = *(const float4*)(buf + 8);
}

// ---------------- spatial-attn conv1 via MFMA (implicit GEMM, split-K=4) ----------------
__global__ void __launch_bounds__(128) k_samfma(const _Float16* __restrict__ Ytg,
                                                const _Float16* __restrict__ Whg,
                                                float* __restrict__ cpart) {
  int wid = threadIdx.x >> 6, lane = threadIdx.x & 63;
  int r = lane & 15, g = lane >> 4;
  int mblk = blockIdx.x;
  int b = mblk >> 3;
  int rowbase = (mblk & 7) * 4 + wid * 2;
  int n0 = blockIdx.y * 64;
  int k0 = blockIdx.z * 512;
  const _Float16* Yb = Ytg + (size_t)b * (1024 * 2048);
  f4 acc[4][4];
#pragma unroll
  for (int mi = 0; mi < 4; ++mi)
#pragma unroll
    for (int ni = 0; ni < 4; ++ni) acc[mi][ni] = (f4){0.f, 0.f, 0.f, 0.f};
  const half8 zero8 = {0, 0, 0, 0, 0, 0, 0, 0};

  for (int kc = 0; kc < 16; ++kc) {
    int ci = k0 + kc * 32 + g * 8;
#pragma unroll
    for (int tap = 0; tap < 9; ++tap) {
      const int dh = tap / 3 - 1, dw = tap % 3 - 1;
      half8 av[4], bv[4];
#pragma unroll
      for (int mi = 0; mi < 4; ++mi) {
        int pr = rowbase + ((mi * 16 + r) >> 5) + dh;
        int pc = ((mi * 16 + r) & 31) + dw;
        bool ok = ((unsigned)pr < 32u) && ((unsigned)pc < 32u);
        const _Float16* ap = Yb + (size_t)((ok ? pr : 0) * 32 + (ok ? pc : 0)) * 2048 + ci;
        half8 v = *(const half8*)ap;
        av[mi] = ok ? v : zero8;
      }
#pragma unroll
      for (int ni = 0; ni < 4; ++ni) {
        int co = n0 + ni * 16 + r;
        bv[ni] = *(const half8*)(Whg + (size_t)(tap * 128 + co) * 2048 + ci);
      }
#pragma unroll
      for (int mi = 0; mi < 4; ++mi)
#pragma unroll
        for (int ni = 0; ni < 4; ++ni)
          acc[mi][ni] = __builtin_amdgcn_mfma_f32_16x16x32_f16(av[mi], bv[ni], acc[mi][ni], 0, 0, 0);
    }
  }
  float* cp = cpart + (size_t)blockIdx.z * (8192 * 128);
  int basepix = b * 1024 + rowbase * 32;
#pragma unroll
  for (int mi = 0; mi < 4; ++mi)
#pragma unroll
    for (int ni = 0; ni < 4; ++ni) {
      int co = n0 + ni * 16 + r;
#pragma unroll
      for (int j = 0; j < 4; ++j)
        cp[(size_t)(basepix + mi * 16 + g * 4 + j) * 128 + co] = acc[mi][ni][j];
    }
}

// ---------------- reduce partials + bias + relu + conv2 + softmax ----------------
__global__ void k_saconv2f(const float* __restrict__ cpart, const float* __restrict__ sab1,
                           const float* __restrict__ saw2, const float* __restrict__ sab2,
                           float* __restrict__ swout) {
  int p = blockIdx.x * 256 + threadIdx.x;
  int b = blockIdx.y;
  int pix = b * 1024 + p;
  const float* c0 = cpart + (size_t)pix * 128;
  float a0 = sab2[0], a1 = sab2[1], a2 = sab2[2], a3 = sab2[3];
  for (int ci = 0; ci < 128; ++ci) {
    float s = c0[ci] + c0[ci + 1048576] + c0[ci + 2097152] + c0[ci + 3145728];
    float v = fmaxf(s + sab1[ci], 0.f);
    a0 = fmaf(v, saw2[ci],       a0);
    a1 = fmaf(v, saw2[128 + ci], a1);
    a2 = fmaf(v, saw2[256 + ci], a2);
    a3 = fmaf(v, saw2[384 + ci], a3);
  }
  float m = fmaxf(fmaxf(a0, a1), fmaxf(a2, a3));
  float e0 = __expf(a0 - m), e1 = __expf(a1 - m), e2 = __expf(a2 - m), e3 = __expf(a3 - m);
  float inv = 1.f / (e0 + e1 + e2 + e3);
  swout[(b * 4 + 0) * 1024 + p] = e0 * inv;
  swout[(b * 4 + 1) * 1024 + p] = e1 * inv;
  swout[(b * 4 + 2) * 1024 + p] = e2 * inv;
  swout[(b * 4 + 3) * 1024 + p] = e3 * inv;
}

// ---------------- channel avg ----------------
__global__ void k_cavg(const float* __restrict__ Y, float* __restrict__ cavg) {
  int gid = blockIdx.x * 256 + threadIdx.x;
  const float4* yr = (const float4*)(Y + (size_t)gid * 1024);
  float s = 0.f;
  for (int i = 0; i < 256; ++i) {
    float4 v = yr[i];
    s += v.x + v.y + v.z + v.w;
  }
  cavg[gid] = s * (1.f / 1024.f);
}

// ---------------- channel attention ----------------
__global__ void k_cw(const float* __restrict__ cavg, const float* __restrict__ caw1,
                     const float* __restrict__ caw2, float* __restrict__ cwout) {
  int b = blockIdx.x;
  int t = threadIdx.x;
  __shared__ float hid[32];
  __shared__ float vv[4];
  if (t < 32) {
    float a = 0.f;
    const float* cv = cavg + b * 2048;
    const float* wr = caw1 + t * 2048;
    for (int i = 0; i < 2048; ++i) a = fmaf(wr[i], cv[i], a);
    hid[t] = fmaxf(a, 0.f);
  }
  __syncthreads();
  if (t < 4) {
    float a = 0.f;
    for (int i = 0; i < 32; ++i) a = fmaf(caw2[t * 32 + i], hid[i], a);
    vv[t] = a;
  }
  __syncthreads();
  if (t < 4) {
    float m = fmaxf(fmaxf(vv[0], vv[1]), fmaxf(vv[2], vv[3]));
    float e = __expf(vv[t] - m);
    float s = __expf(vv[0] - m) + __expf(vv[1] - m) + __expf(vv[2] - m) + __expf(vv[3] - m);
    cwout[b * 4 + t] = e / s;
  }
}

// ---------------- catH: spatial/channel mixes -> fp16 pix-major concat ----------------
__global__ void __launch_bounds__(256) k_catH(const float* __restrict__ Y,
                                              const float* __restrict__ swv,
                                              const float* __restrict__ cwv,
                                              _Float16* __restrict__ catH) {
  __shared__ float sm_s[64][65];
  __shared__ float sm_c[64][65];
  int p0 = blockIdx.x * 64, c0 = blockIdx.y * 64, b = blockIdx.z;
  float cwr[4];
#pragma unroll
  for (int r = 0; r < 4; ++r) cwr[r] = cwv[b * 4 + r];
#pragma unroll
  for (int i = 0; i < 16; ++i) {
    int idx = threadIdx.x + i * 256;
    int cc = idx >> 6, pp = idx & 63;
    float s = 0.f, ca = 0.f;
#pragma unroll
    for (int r = 0; r < 4; ++r) {
      float v = Y[((size_t)(b * 4 + r) * 512 + c0 + cc) * 1024 + p0 + pp];
      s  = fmaf(v, swv[(size_t)(b * 4 + r) * 1024 + p0 + pp], s);
      ca = fmaf(v, cwr[r], ca);
    }
    sm_s[cc][pp] = s; sm_c[cc][pp] = ca;
  }
  __syncthreads();
#pragma unroll
  for (int i = 0; i < 16; ++i) {
    int idx = threadIdx.x + i * 256;
    int pp = idx >> 6, cc = idx & 63;
    _Float16* dst = catH + ((size_t)(b * 1024) + p0 + pp) * 1024;
    dst[c0 + cc]       = (_Float16)sm_s[cc][pp];
    dst[512 + c0 + cc] = (_Float16)sm_c[cc][pp];
  }
}

// ---------------- gate 1x1 conv (1024->512) via MFMA + sigmoid fuse -> fusedH ----------------
__global__ void __launch_bounds__(256) k_gatemfma(const _Float16* __restrict__ catH,
                                                  const _Float16* __restrict__ gwH,
                                                  const float* __restrict__ gb,
                                                  _Float16* __restrict__ fusedH) {
  int wid = threadIdx.x >> 6, lane = threadIdx.x & 63;
  int r = lane & 15, g = lane >> 4;
  int p0 = blockIdx.x * 128 + (wid >> 1) * 64;
  int c0 = blockIdx.y * 128 + (wid & 1) * 64;
  int b  = blockIdx.z;
  const _Float16* Cb = catH + (size_t)b * (1024 * 1024);
  f4 acc[4][4];
#pragma unroll
  for (int mi = 0; mi < 4; ++mi)
#pragma unroll
    for (int ni = 0; ni < 4; ++ni) acc[mi][ni] = (f4){0.f, 0.f, 0.f, 0.f};
  for (int kk = 0; kk < 1024; kk += 32) {
    half8 av[4], bv[4];
#pragma unroll
    for (int mi = 0; mi < 4; ++mi)
      av[mi] = *(const half8*)(Cb + (size_t)(p0 + mi * 16 + r) * 1024 + kk + g * 8);
#pragma unroll
    for (int ni = 0; ni < 4; ++ni)
      bv[ni] = *(const half8*)(gwH + (size_t)(c0 + ni * 16 + r) * 1024 + kk + g * 8);
#pragma unroll
    for (int mi = 0; mi < 4; ++mi)
#pragma unroll
      for (int ni = 0; ni < 4; ++ni)
        acc[mi][ni] = __builtin_amdgcn_mfma_f32_16x16x32_f16(av[mi], bv[ni], acc[mi][ni], 0, 0, 0);
  }
#pragma unroll
  for (int ni = 0; ni < 4; ++ni) {
    int c = c0 + ni * 16 + r;
    float bias = gb[c];
#pragma unroll
    for (int mi = 0; mi < 4; ++mi)
#pragma unroll
      for (int j = 0; j < 4; ++j) {
        int pix = p0 + mi * 16 + g * 4 + j;
        const _Float16* rowp = Cb + (size_t)pix * 1024 + c;
        float sp = (float)rowp[0], ch = (float)rowp[512];
        float gt = sigmoidf_(acc[mi][ni][j] + bias);
        fusedH[((size_t)(b * 1024) + pix) * 512 + c] = (_Float16)(gt * sp + (1.f - gt) * ch);
      }
  }
}

// ---------------- out_proj (512->256) via MFMA + GELU ----------------
__global__ void __launch_bounds__(256) k_outprojmfma(const _Float16* __restrict__ fusedH,
                                                     const _Float16* __restrict__ opH,
                                                     float* __restrict__ out) {
  int wid = threadIdx.x >> 6, lane = threadIdx.x & 63;
  int r = lane & 15, g = lane >> 4;
  int m0 = blockIdx.x * 64;                 // cout
  int n0 = blockIdx.y * 256 + wid * 64;     // pix
  int b  = blockIdx.z;
  f4 acc[4][4];
#pragma unroll
  for (int mi = 0; mi < 4; ++mi)
#pragma unroll
    for (int ni = 0; ni < 4; ++ni) acc[mi][ni] = (f4){0.f, 0.f, 0.f, 0.f};
  for (int kk = 0; kk < 512; kk += 32) {
    half8 av[4], bv[4];
#pragma unroll
    for (int mi = 0; mi < 4; ++mi)
      av[mi] = *(const half8*)(opH + (size_t)(m0 + mi * 16 + r) * 512 + kk + g * 8);
#pragma unroll
    for (int ni = 0; ni < 4; ++ni)
      bv[ni] = *(const half8*)(fusedH + ((size_t)(b * 1024) + n0 + ni * 16 + r) * 512 + kk + g * 8);
#pragma unroll
    for (int mi = 0; mi < 4; ++mi)
#pragma unroll
      for (int ni = 0; ni < 4; ++ni)
        acc[mi][ni] = __builtin_amdgcn_mfma_f32_16x16x32_f16(av[mi], bv[ni], acc[mi][ni], 0, 0, 0);
  }
#pragma unroll
  for (int mi = 0; mi < 4; ++mi)
#pragma unroll
    for (int ni = 0; ni < 4; ++ni) {
      int pix = n0 + ni * 16 + r;
#pragma unroll
      for (int j = 0; j < 4; ++j) {
        int co = m0 + mi * 16 + g * 4 + j;
        out[((size_t)(b * 256) + co) * 1024 + pix] = geluf(acc[mi][ni][j]);
      }
    }
}

extern "C" void kernel_launch(void* const* d_in, const int* in_sizes, int n_in,
                              void* d_out, int out_size, void* d_ws, size_t ws_size,
                              hipStream_t stream) {
  const float* x    = (const float*)d_in[0];
  const float* inw  = (const float*)d_in[1];
  const float* opw  = (const float*)d_in[2];
  const float* cxw  = (const float*)d_in[3];
  const float* cxb  = (const float*)d_in[4];
  const float* czw  = (const float*)d_in[5];
  const float* czb  = (const float*)d_in[6];
  const float* xpw  = (const float*)d_in[7];
  const float* dtw  = (const float*)d_in[8];
  const float* dtb  = (const float*)d_in[9];
  const float* alog = (const float*)d_in[10];
  const float* ds   = (const float*)d_in[11];
  const float* saw1 = (const float*)d_in[12];
  const float* sab1 = (const float*)d_in[13];
  const float* saw2 = (const float*)d_in[14];
  const float* sab2 = (const float*)d_in[15];
  const float* caw1 = (const float*)d_in[16];
  const float* caw2 = (const float*)d_in[17];
  const float* gw   = (const float*)d_in[18];
  const float* gb   = (const float*)d_in[19];

  float* ws = (float*)d_ws;
  float* xz   = ws + 0;          //  4,194,304  [alias: scan carries -> Cpart -> fusedH]
  float* xseq = ws + 4194304;    //  8,388,608  [alias: Ytg fp16 -> catH fp16]
  float* xdbl = ws + 12582912;   //  1,572,864
  float* Y    = ws + 14155776;   // 16,777,216
  float* swb  = ws + 31981568;   //     32,768
  float* cavg = ws + 32014336;   //     16,384
  float* cwb  = ws + 32030720;   //         32
  float* inWT = ws + 32030752;   //    131,072
  float* opHF = ws + 32161824;   //    131,072 (opH fp16: 131,072 halves)
  float* gwHF = ws + 32292896;   //    524,288 (gwH fp16: 524,288 halves)
  float* WhgF = ws + 32817184;   //  1,179,648 (Whg fp16: 2,359,296 halves)
  float* aprodg = xz;            //  2,097,152
  float* hcarg  = xz + 2097152;  //  2,097,152
  float* Cpart = xz;
  _Float16* Ytg   = (_Float16*)xseq;
  _Float16* catH  = (_Float16*)xseq;      // after samfma consumed Ytg
  _Float16* fusedH= (_Float16*)xz;        // after saconv2f consumed Cpart
  _Float16* Whg = (_Float16*)WhgF;
  _Float16* gwH = (_Float16*)gwHF;
  _Float16* opH = (_Float16*)opHF;

  k_prep<<<3072, 256, 0, stream>>>(inw, gw, opw, inWT, gwH, opH);
  k_wprep<<<9216, 256, 0, stream>>>(saw1, Whg);
  k_inproj<<<dim3(128, 8), 512, 0, stream>>>(x, inWT, xz);
  k_convx<<<dim3(4, 1024, 8), 256, 0, stream>>>(xz, cxw, cxb, xseq);
  k_convz<<<dim3(4, 1024, 8), 256, 0, stream>>>(xz, czw, czb, Y);
  k_xdbl<<<dim3(4, 48, 32), 256, 0, stream>>>(xseq, xpw, xdbl);
  k_scanA<<<dim3(16, 32), 256, 0, stream>>>(xseq, xdbl, dtw, dtb, alog, aprodg, hcarg);
  k_scanB<<<512, 256, 0, stream>>>(aprodg, hcarg);
  k_scanC<<<dim3(16, 32), 256, 0, stream>>>(xseq, xdbl, dtw, dtb, alog, ds, hcarg, Y);
  k_ytr<<<dim3(8, 64, 8), 256, 0, stream>>>(Y, Ytg);
  k_samfma<<<dim3(64, 2, 4), 128, 0, stream>>>(Ytg, Whg, Cpart);
  k_saconv2f<<<dim3(4, 8), 256, 0, stream>>>(Cpart, sab1, saw2, sab2, swb);
  k_cavg<<<64, 256, 0, stream>>>(Y, cavg);
  k_cw<<<8, 64, 0, stream>>>(cavg, caw1, caw2, cwb);
  k_catH<<<dim3(16, 8, 8), 256, 0, stream>>>(Y, swb, cwb, catH);
  k_gatemfma<<<dim3(8, 4, 8), 256, 0, stream>>>(catH, gwH, gb, fusedH);
  k_outprojmfma<<<dim3(4, 4, 8), 256, 0, stream>>>(fusedH, opH, (float*)d_out);
}

// Round 5
// 640.239 us; speedup vs baseline: 6.1437x; 1.1225x over previous
//
#include <hip/hip_runtime.h>
#include <math.h>

// dims: B=8, DM=256, H=W=32, L=HW=1024, R=4, DI=512, DH=256, N=16, K=4, DTR=16

typedef _Float16 half8 __attribute__((ext_vector_type(8)));
typedef float f4 __attribute__((ext_vector_type(4)));

__device__ __forceinline__ int srcmap(int r, int l) {
  int i = l >> 5, j = l & 31;
  int h, w;
  if (r == 0)      { h = i;      w = j;      }
  else if (r == 1) { h = j;      w = 31 - i; }
  else if (r == 2) { h = 31 - i; w = 31 - j; }
  else             { h = 31 - j; w = i;      }
  return (h << 5) + w;
}

__device__ __forceinline__ float siluf(float x)    { return x / (1.f + __expf(-x)); }
__device__ __forceinline__ float sigmoidf_(float x){ return 1.f / (1.f + __expf(-x)); }
__device__ __forceinline__ float geluf(float x) {
  float x3 = x * x * x;
  return 0.5f * x * (1.f + tanhf(0.7978845608028654f * (x + 0.044715f * x3)));
}

// ---------------- prep: inWT fp32 transpose; gwH/opH fp16 casts (native layout) ----------------
__global__ void k_prep(const float* __restrict__ inw, const float* __restrict__ gw,
                       const float* __restrict__ opw,
                       float* __restrict__ inWT, _Float16* __restrict__ gwH,
                       _Float16* __restrict__ opH) {
  int idx = blockIdx.x * 256 + threadIdx.x;
  if (idx < 131072) {
    int c = idx >> 9, d = idx & 511;
    inWT[idx] = inw[d * 256 + c];
  } else if (idx < 655360) {
    int i = idx - 131072;
    gwH[i] = (_Float16)gw[i];
  } else {
    int i = idx - 655360;
    opH[i] = (_Float16)opw[i];
  }
}

// ---------------- fp16 pack of sa_w1: Whg[tap][co][ci] ----------------
__global__ void k_wprep(const float* __restrict__ saw1, _Float16* __restrict__ Whg) {
  int o = blockIdx.x * 256 + threadIdx.x;
  int ci = o & 2047;
  int co = (o >> 11) & 127;
  int tap = o >> 18;
  Whg[o] = (_Float16)saw1[((size_t)co * 2048 + ci) * 9 + tap];
}

// ---------------- in_proj ----------------
__global__ void __launch_bounds__(512) k_inproj(const float* __restrict__ x,
                                                const float* __restrict__ inWT,
                                                float* __restrict__ xz) {
  int d = threadIdx.x;
  int b = blockIdx.y;
  int p0 = blockIdx.x * 8;
  const float* xb = x + (size_t)(b * 256) * 1024 + p0;
  float acc[8];
#pragma unroll
  for (int j = 0; j < 8; ++j) acc[j] = 0.f;
  for (int c = 0; c < 256; ++c) {
    float w = inWT[c * 512 + d];
    const float* xr = xb + c * 1024;
    float4 a  = *(const float4*)xr;
    float4 b4 = *(const float4*)(xr + 4);
    acc[0] = fmaf(w, a.x,  acc[0]); acc[1] = fmaf(w, a.y,  acc[1]);
    acc[2] = fmaf(w, a.z,  acc[2]); acc[3] = fmaf(w, a.w,  acc[3]);
    acc[4] = fmaf(w, b4.x, acc[4]); acc[5] = fmaf(w, b4.y, acc[5]);
    acc[6] = fmaf(w, b4.z, acc[6]); acc[7] = fmaf(w, b4.w, acc[7]);
  }
  float* o = xz + (size_t)(b * 512 + d) * 1024 + p0;
  float4 o0 = {acc[0], acc[1], acc[2], acc[3]};
  float4 o1 = {acc[4], acc[5], acc[6], acc[7]};
  *(float4*)o = o0; *(float4*)(o + 4) = o1;
}

// ---------------- depthwise conv1d + SiLU (x-half) -> rotated seq ----------------
__global__ void k_convx(const float* __restrict__ xz, const float* __restrict__ cw,
                        const float* __restrict__ cb, float* __restrict__ xseq) {
  int l  = blockIdx.x * 256 + threadIdx.x;
  int rd = blockIdx.y; int r = rd >> 8; int d = rd & 255;
  int b  = blockIdx.z;
  float w0 = cw[rd*4+0], w1 = cw[rd*4+1], w2 = cw[rd*4+2], w3 = cw[rd*4+3];
  float acc = cb[rd];
  const float* src = xz + (size_t)(b * 512 + d) * 1024;
  if (l - 1 >= 0)   acc = fmaf(w0, src[srcmap(r, l - 1)], acc);
  acc = fmaf(w1, src[srcmap(r, l)], acc);
  if (l + 1 < 1024) acc = fmaf(w2, src[srcmap(r, l + 1)], acc);
  if (l + 2 < 1024) acc = fmaf(w3, src[srcmap(r, l + 2)], acc);
  xseq[((size_t)(b * 4 + r) * 256 + d) * 1024 + l] = siluf(acc);
}

// z-half -> Y z-rows in ROTATED (seq) order, linear coalesced write
__global__ void k_convz(const float* __restrict__ xz, const float* __restrict__ cw,
                        const float* __restrict__ cb, float* __restrict__ Y) {
  int l  = blockIdx.x * 256 + threadIdx.x;
  int rd = blockIdx.y; int r = rd >> 8; int d = rd & 255;
  int b  = blockIdx.z;
  float w0 = cw[rd*4+0], w1 = cw[rd*4+1], w2 = cw[rd*4+2], w3 = cw[rd*4+3];
  float acc = cb[rd];
  const float* src = xz + (size_t)(b * 512 + 256 + d) * 1024;
  if (l - 1 >= 0)   acc = fmaf(w0, src[srcmap(r, l - 1)], acc);
  acc = fmaf(w1, src[srcmap(r, l)], acc);
  if (l + 1 < 1024) acc = fmaf(w2, src[srcmap(r, l + 1)], acc);
  if (l + 2 < 1024) acc = fmaf(w3, src[srcmap(r, l + 2)], acc);
  Y[((size_t)(b * 4 + r) * 512 + 256 + d) * 1024 + l] = siluf(acc);
}

// ---------------- x_dbl, k-major tiles: xdT[br][ch][32c][48k] ----------------
__global__ void __launch_bounds__(256) k_xdblT(const float* __restrict__ xseq,
                                               const float* __restrict__ xpw,
                                               float* __restrict__ xdT) {
  int ch = blockIdx.x;          // 0..31
  int br = blockIdx.y;          // 0..31
  int r  = br & 3;
  int c  = threadIdx.x & 31;
  int kq = threadIdx.x >> 5;    // 0..7, 6 k each
  const float* xs = xseq + (size_t)(br * 256) * 1024 + ch * 32 + c;
  const float* w  = xpw + (r * 48 + kq * 6) * 256;
  float acc[6] = {0.f, 0.f, 0.f, 0.f, 0.f, 0.f};
  for (int d = 0; d < 256; ++d) {
    float xv = xs[(size_t)d * 1024];
#pragma unroll
    for (int j = 0; j < 6; ++j) acc[j] = fmaf(w[j * 256 + d], xv, acc[j]);
  }
  float* o = xdT + ((size_t)(br * 32 + ch) * 32 + c) * 48 + kq * 6;
#pragma unroll
  for (int j = 0; j < 6; ++j) o[j] = acc[j];
}

// ---------------- chunked selective scan (chunk=32) ----------------
// Pass A: chunk-local (h0=0) end-state + a-product. Carry stored INSIDE the
// Y slots this (br,ch) block's scanC will overwrite; aprod in xz.
__global__ void __launch_bounds__(256) k_scanA(
    const float* __restrict__ xseq, const float* __restrict__ xdT,
    const float* __restrict__ dtw_, const float* __restrict__ dtb_,
    const float* __restrict__ alogs,
    float* __restrict__ aprodg, float* __restrict__ Yc) {
  int ch = blockIdx.x;
  int br = blockIdx.y; int r = br & 3;
  int d  = threadIdx.x;
  int rd = r * 256 + d;
  f4 w0 = *(const f4*)&dtw_[rd * 16], w1 = *(const f4*)&dtw_[rd * 16 + 4],
     w2 = *(const f4*)&dtw_[rd * 16 + 8], w3 = *(const f4*)&dtw_[rd * 16 + 12];
  float A2[16], h[16], ap[16];
#pragma unroll
  for (int n = 0; n < 16; ++n) A2[n] = -__expf(alogs[rd * 16 + n]) * 1.44269504f;
#pragma unroll
  for (int n = 0; n < 16; ++n) { h[n] = 0.f; ap[n] = 1.f; }
  float bias = dtb_[rd];
  __shared__ __align__(16) float t2[1536];   // [32c][48k]
  const float* xd = xdT + (size_t)(br * 32 + ch) * 1536;
  for (int i = threadIdx.x; i < 384; i += 256) ((f4*)t2)[i] = ((const f4*)xd)[i];
  __syncthreads();
  const float* us = xseq + (size_t)(br * 256 + d) * 1024 + ch * 32;
  for (int c4 = 0; c4 < 8; ++c4) {
    float4 uv = *(const float4*)(us + c4 * 4);
    float uarr[4] = {uv.x, uv.y, uv.z, uv.w};
#pragma unroll
    for (int cc = 0; cc < 4; ++cc) {
      const f4* row = (const f4*)&t2[(c4 * 4 + cc) * 48];
      f4 td0 = row[0], td1 = row[1], td2 = row[2], td3 = row[3];
      float delta = bias
        + td0[0]*w0[0] + td0[1]*w0[1] + td0[2]*w0[2] + td0[3]*w0[3]
        + td1[0]*w1[0] + td1[1]*w1[1] + td1[2]*w1[2] + td1[3]*w1[3]
        + td2[0]*w2[0] + td2[1]*w2[1] + td2[2]*w2[2] + td2[3]*w2[3]
        + td3[0]*w3[0] + td3[1]*w3[1] + td3[2]*w3[2] + td3[3]*w3[3];
      float sp = (delta > 20.f) ? delta : __logf(1.f + __expf(delta));
      float du = sp * uarr[cc];
      f4 tb[4] = {row[4], row[5], row[6], row[7]};
#pragma unroll
      for (int n = 0; n < 16; ++n) {
        float e = exp2f(sp * A2[n]);
        h[n] = fmaf(e, h[n], du * tb[n >> 2][n & 3]);
        ap[n] *= e;
      }
    }
  }
  float* apo = aprodg + ((size_t)(br * 32 + ch) * 256 + d) * 16;
  float* hco = Yc + (size_t)(br * 512 + d) * 1024 + ch * 32;
#pragma unroll
  for (int n = 0; n < 16; ++n) { apo[n] = ap[n]; hco[n] = h[n]; }
}

// Pass B: prefix over 32 chunks -> chunk-INCOMING states, in place (in Y slots)
__global__ void k_scanB(const float* __restrict__ aprodg, float* __restrict__ Yc) {
  int t  = blockIdx.x * 256 + threadIdx.x;   // 131072 = br*4096 + d*16 + n
  int br = t >> 12;
  int dn = t & 4095;
  int d = dn >> 4, n = dn & 15;
  float h = 0.f;
  for (int c = 0; c < 32; ++c) {
    size_t ao = (size_t)(br * 32 + c) * 4096 + dn;
    size_t yo = (size_t)(br * 512 + d) * 1024 + c * 32 + n;
    float hin = h;
    h = fmaf(aprodg[ao], h, Yc[yo]);
    Yc[yo] = hin;
  }
}

// Pass C: re-run chunk seeded with true h0, emit y in ROTATED layout, coalesced
__global__ void __launch_bounds__(256) k_scanC(
    const float* __restrict__ xseq, const float* __restrict__ xdT,
    const float* __restrict__ dtw_, const float* __restrict__ dtb_,
    const float* __restrict__ alogs, const float* __restrict__ ds_,
    float* __restrict__ Y) {
  int ch = blockIdx.x;
  int br = blockIdx.y; int r = br & 3;
  int d  = threadIdx.x;
  int rd = r * 256 + d;
  f4 w0 = *(const f4*)&dtw_[rd * 16], w1 = *(const f4*)&dtw_[rd * 16 + 4],
     w2 = *(const f4*)&dtw_[rd * 16 + 8], w3 = *(const f4*)&dtw_[rd * 16 + 12];
  float A2[16], h[16];
#pragma unroll
  for (int n = 0; n < 16; ++n) A2[n] = -__expf(alogs[rd * 16 + n]) * 1.44269504f;
  float bias = dtb_[rd];
  float dsv  = ds_[rd];
  __shared__ __align__(16) float t2[1536];
  __shared__ float yt[32][257];
  const float* xd = xdT + (size_t)(br * 32 + ch) * 1536;
  for (int i = threadIdx.x; i < 384; i += 256) ((f4*)t2)[i] = ((const f4*)xd)[i];
  float* ybase = Y + (size_t)(br * 512 + d) * 1024 + ch * 32;
#pragma unroll
  for (int n = 0; n < 16; ++n) h[n] = ybase[n];     // embedded carry
  __syncthreads();
  const float* us = xseq + (size_t)(br * 256 + d) * 1024 + ch * 32;
  for (int c4 = 0; c4 < 8; ++c4) {
    float4 uv = *(const float4*)(us + c4 * 4);
    float uarr[4] = {uv.x, uv.y, uv.z, uv.w};
#pragma unroll
    for (int cc = 0; cc < 4; ++cc) {
      int c = c4 * 4 + cc;
      const f4* row = (const f4*)&t2[c * 48];
      f4 td0 = row[0], td1 = row[1], td2 = row[2], td3 = row[3];
      float delta = bias
        + td0[0]*w0[0] + td0[1]*w0[1] + td0[2]*w0[2] + td0[3]*w0[3]
        + td1[0]*w1[0] + td1[1]*w1[1] + td1[2]*w1[2] + td1[3]*w1[3]
        + td2[0]*w2[0] + td2[1]*w2[1] + td2[2]*w2[2] + td2[3]*w2[3]
        + td3[0]*w3[0] + td3[1]*w3[1] + td3[2]*w3[2] + td3[3]*w3[3];
      float sp = (delta > 20.f) ? delta : __logf(1.f + __expf(delta));
      float du = sp * uarr[cc];
      f4 tb[4] = {row[4], row[5], row[6], row[7]};
      f4 tc[4] = {row[8], row[9], row[10], row[11]};
      float acc = 0.f;
#pragma unroll
      for (int n = 0; n < 16; ++n) {
        float e = exp2f(sp * A2[n]);
        h[n] = fmaf(e, h[n], du * tb[n >> 2][n & 3]);
        acc  = fmaf(h[n], tc[n >> 2][n & 3], acc);
      }
      yt[c][d] = fmaf(dsv, uarr[cc], acc);
    }
  }
  __syncthreads();
  for (int i = threadIdx.x; i < 2048; i += 256) {
    int dd = i >> 3, lq = i & 7;
    f4 v = {yt[lq * 4 + 0][dd], yt[lq * 4 + 1][dd], yt[lq * 4 + 2][dd], yt[lq * 4 + 3][dd]};
    *(f4*)(Y + (size_t)(br * 512 + dd) * 1024 + ch * 32 + lq * 4) = v;
  }
}

// ---------------- Y(rotated) -> fp16 un-rotated pix-major Ytg[b][pix][ci] ----------------
__global__ void k_ytr(const float* __restrict__ Y, _Float16* __restrict__ Ytg) {
  __shared__ float t[32][132];
  int l0  = blockIdx.x * 128;
  int ci0 = blockIdx.y * 32;
  int b   = blockIdx.z;
  int r   = ci0 >> 9;
  const float* src = Y + ((size_t)(b * 2048 + ci0)) * 1024 + l0;
#pragma unroll
  for (int i = 0; i < 16; ++i) {
    int idx = threadIdx.x + i * 256;
    int ci = idx >> 7, pp = idx & 127;
    t[ci][pp] = src[(size_t)ci * 1024 + pp];
  }
  __syncthreads();
  int pp = threadIdx.x >> 1;
  int ch = (threadIdx.x & 1) * 16;
  _Float16 buf[16];
#pragma unroll
  for (int j = 0; j < 16; ++j) buf[j] = (_Float16)t[ch + j][pp];
  int pix = srcmap(r, l0 + pp);
  _Float16* dst = Ytg + ((size_t)(b * 1024) + pix) * 2048 + ci0 + ch;
  *(float4*)dst = *(const float4*)buf;
  *(float4*)(dst + 8) = *(const float4*)(buf + 8);
}

// ---------------- spatial-attn conv1 via MFMA (implicit GEMM, split-K=4) ----------------
__global__ void __launch_bounds__(128) k_samfma(const _Float16* __restrict__ Ytg,
                                                const _Float16* __restrict__ Whg,
                                                float* __restrict__ cpart) {
  int wid = threadIdx.x >> 6, lane = threadIdx.x & 63;
  int r = lane & 15, g = lane >> 4;
  int mblk = blockIdx.x;
  int b = mblk >> 3;
  int rowbase = (mblk & 7) * 4 + wid * 2;
  int n0 = blockIdx.y * 64;
  int k0 = blockIdx.z * 512;
  const _Float16* Yb = Ytg + (size_t)b * (1024 * 2048);
  f4 acc[4][4];
#pragma unroll
  for (int mi = 0; mi < 4; ++mi)
#pragma unroll
    for (int ni = 0; ni < 4; ++ni) acc[mi][ni] = (f4){0.f, 0.f, 0.f, 0.f};
  const half8 zero8 = {0, 0, 0, 0, 0, 0, 0, 0};

  for (int kc = 0; kc < 16; ++kc) {
    int ci = k0 + kc * 32 + g * 8;
#pragma unroll
    for (int tap = 0; tap < 9; ++tap) {
      const int dh = tap / 3 - 1, dw = tap % 3 - 1;
      half8 av[4], bv[4];
#pragma unroll
      for (int mi = 0; mi < 4; ++mi) {
        int pr = rowbase + ((mi * 16 + r) >> 5) + dh;
        int pc = ((mi * 16 + r) & 31) + dw;
        bool ok = ((unsigned)pr < 32u) && ((unsigned)pc < 32u);
        const _Float16* ap = Yb + (size_t)((ok ? pr : 0) * 32 + (ok ? pc : 0)) * 2048 + ci;
        half8 v = *(const half8*)ap;
        av[mi] = ok ? v : zero8;
      }
#pragma unroll
      for (int ni = 0; ni < 4; ++ni) {
        int co = n0 + ni * 16 + r;
        bv[ni] = *(const half8*)(Whg + (size_t)(tap * 128 + co) * 2048 + ci);
      }
#pragma unroll
      for (int mi = 0; mi < 4; ++mi)
#pragma unroll
        for (int ni = 0; ni < 4; ++ni)
          acc[mi][ni] = __builtin_amdgcn_mfma_f32_16x16x32_f16(av[mi], bv[ni], acc[mi][ni], 0, 0, 0);
    }
  }
  float* cp = cpart + (size_t)blockIdx.z * (8192 * 128);
  int basepix = b * 1024 + rowbase * 32;
#pragma unroll
  for (int mi = 0; mi < 4; ++mi)
#pragma unroll
    for (int ni = 0; ni < 4; ++ni) {
      int co = n0 + ni * 16 + r;
#pragma unroll
      for (int j = 0; j < 4; ++j)
        cp[(size_t)(basepix + mi * 16 + g * 4 + j) * 128 + co] = acc[mi][ni][j];
    }
}

// ---------------- reduce partials + bias + relu + conv2 + softmax ----------------
__global__ void k_saconv2f(const float* __restrict__ cpart, const float* __restrict__ sab1,
                           const float* __restrict__ saw2, const float* __restrict__ sab2,
                           float* __restrict__ swout) {
  int p = blockIdx.x * 256 + threadIdx.x;
  int b = blockIdx.y;
  int pix = b * 1024 + p;
  const float* c0 = cpart + (size_t)pix * 128;
  float a0 = sab2[0], a1 = sab2[1], a2 = sab2[2], a3 = sab2[3];
  for (int ci = 0; ci < 128; ++ci) {
    float s = c0[ci] + c0[ci + 1048576] + c0[ci + 2097152] + c0[ci + 3145728];
    float v = fmaxf(s + sab1[ci], 0.f);
    a0 = fmaf(v, saw2[ci],       a0);
    a1 = fmaf(v, saw2[128 + ci], a1);
    a2 = fmaf(v, saw2[256 + ci], a2);
    a3 = fmaf(v, saw2[384 + ci], a3);
  }
  float m = fmaxf(fmaxf(a0, a1), fmaxf(a2, a3));
  float e0 = __expf(a0 - m), e1 = __expf(a1 - m), e2 = __expf(a2 - m), e3 = __expf(a3 - m);
  float inv = 1.f / (e0 + e1 + e2 + e3);
  swout[(b * 4 + 0) * 1024 + p] = e0 * inv;
  swout[(b * 4 + 1) * 1024 + p] = e1 * inv;
  swout[(b * 4 + 2) * 1024 + p] = e2 * inv;
  swout[(b * 4 + 3) * 1024 + p] = e3 * inv;
}

// ---------------- channel avg (permutation-invariant over pixels) ----------------
__global__ void k_cavg(const float* __restrict__ Y, float* __restrict__ cavg) {
  int gid = blockIdx.x * 256 + threadIdx.x;
  const float4* yr = (const float4*)(Y + (size_t)gid * 1024);
  float s = 0.f;
  for (int i = 0; i < 256; ++i) {
    float4 v = yr[i];
    s += v.x + v.y + v.z + v.w;
  }
  cavg[gid] = s * (1.f / 1024.f);
}

// ---------------- channel attention ----------------
__global__ void k_cw(const float* __restrict__ cavg, const float* __restrict__ caw1,
                     const float* __restrict__ caw2, float* __restrict__ cwout) {
  int b = blockIdx.x;
  int t = threadIdx.x;
  __shared__ float hid[32];
  __shared__ float vv[4];
  if (t < 32) {
    float a = 0.f;
    const float* cv = cavg + b * 2048;
    const float* wr = caw1 + t * 2048;
    for (int i = 0; i < 2048; ++i) a = fmaf(wr[i], cv[i], a);
    hid[t] = fmaxf(a, 0.f);
  }
  __syncthreads();
  if (t < 4) {
    float a = 0.f;
    for (int i = 0; i < 32; ++i) a = fmaf(caw2[t * 32 + i], hid[i], a);
    vv[t] = a;
  }
  __syncthreads();
  if (t < 4) {
    float m = fmaxf(fmaxf(vv[0], vv[1]), fmaxf(vv[2], vv[3]));
    float e = __expf(vv[t] - m);
    float s = __expf(vv[0] - m) + __expf(vv[1] - m) + __expf(vv[2] - m) + __expf(vv[3] - m);
    cwout[b * 4 + t] = e / s;
  }
}

// ---------------- catH: mixes from Ytg (fp16, un-rotated) -> fp16 pix-major concat ----------------
__global__ void __launch_bounds__(256) k_catH(const _Float16* __restrict__ Ytg,
                                              const float* __restrict__ swv,
                                              const float* __restrict__ cwv,
                                              _Float16* __restrict__ catO) {
  int p0 = blockIdx.x * 64, c0 = blockIdx.y * 64, b = blockIdx.z;
  int pp = threadIdx.x >> 2, cs = (threadIdx.x & 3) * 16;
  int pix = p0 + pp;
  const _Float16* src = Ytg + (size_t)(b * 1024 + pix) * 2048 + c0 + cs;
  float accS[16], accC[16];
#pragma unroll
  for (int j = 0; j < 16; ++j) { accS[j] = 0.f; accC[j] = 0.f; }
#pragma unroll
  for (int r = 0; r < 4; ++r) {
    half8 v0 = *(const half8*)(src + r * 512);
    half8 v1 = *(const half8*)(src + r * 512 + 8);
    float sw = swv[(size_t)(b * 4 + r) * 1024 + pix];
    float cw = cwv[b * 4 + r];
#pragma unroll
    for (int j = 0; j < 8; ++j) {
      float f0 = (float)v0[j], f1 = (float)v1[j];
      accS[j]     = fmaf(f0, sw, accS[j]);
      accS[j + 8] = fmaf(f1, sw, accS[j + 8]);
      accC[j]     = fmaf(f0, cw, accC[j]);
      accC[j + 8] = fmaf(f1, cw, accC[j + 8]);
    }
  }
  _Float16 os[16], oc[16];
#pragma unroll
  for (int j = 0; j < 16; ++j) { os[j] = (_Float16)accS[j]; oc[j] = (_Float16)accC[j]; }
  _Float16* dst = catO + ((size_t)(b * 1024) + pix) * 1024;
  *(half8*)(dst + c0 + cs)       = *(half8*)os;
  *(half8*)(dst + c0 + cs + 8)   = *(half8*)(os + 8);
  *(half8*)(dst + 512 + c0 + cs)     = *(half8*)oc;
  *(half8*)(dst + 512 + c0 + cs + 8) = *(half8*)(oc + 8);
}

// ---------------- gate 1x1 conv (1024->512) via MFMA + sigmoid fuse -> fusedH ----------------
__global__ void __launch_bounds__(256) k_gatemfma(const _Float16* __restrict__ catO,
                                                  const _Float16* __restrict__ gwH,
                                                  const float* __restrict__ gb,
                                                  _Float16* __restrict__ fusedH) {
  int wid = threadIdx.x >> 6, lane = threadIdx.x & 63;
  int r = lane & 15, g = lane >> 4;
  int p0 = blockIdx.x * 128 + (wid >> 1) * 64;
  int c0 = blockIdx.y * 128 + (wid & 1) * 64;
  int b  = blockIdx.z;
  const _Float16* Cb = catO + (size_t)b * (1024 * 1024);
  f4 acc[4][4];
#pragma unroll
  for (int mi = 0; mi < 4; ++mi)
#pragma unroll
    for (int ni = 0; ni < 4; ++ni) acc[mi][ni] = (f4){0.f, 0.f, 0.f, 0.f};
  for (int kk = 0; kk < 1024; kk += 32) {
    half8 av[4], bv[4];
#pragma unroll
    for (int mi = 0; mi < 4; ++mi)
      av[mi] = *(const half8*)(Cb + (size_t)(p0 + mi * 16 + r) * 1024 + kk + g * 8);
#pragma unroll
    for (int ni = 0; ni < 4; ++ni)
      bv[ni] = *(const half8*)(gwH + (size_t)(c0 + ni * 16 + r) * 1024 + kk + g * 8);
#pragma unroll
    for (int mi = 0; mi < 4; ++mi)
#pragma unroll
      for (int ni = 0; ni < 4; ++ni)
        acc[mi][ni] = __builtin_amdgcn_mfma_f32_16x16x32_f16(av[mi], bv[ni], acc[mi][ni], 0, 0, 0);
  }
#pragma unroll
  for (int ni = 0; ni < 4; ++ni) {
    int c = c0 + ni * 16 + r;
    float bias = gb[c];
#pragma unroll
    for (int mi = 0; mi < 4; ++mi)
#pragma unroll
      for (int j = 0; j < 4; ++j) {
        int pix = p0 + mi * 16 + g * 4 + j;
        const _Float16* rowp = Cb + (size_t)pix * 1024 + c;
        float sp = (float)rowp[0], ch = (float)rowp[512];
        float gt = sigmoidf_(acc[mi][ni][j] + bias);
        fusedH[((size_t)(b * 1024) + pix) * 512 + c] = (_Float16)(gt * sp + (1.f - gt) * ch);
      }
  }
}

// ---------------- out_proj (512->256) via MFMA + GELU ----------------
__global__ void __launch_bounds__(256) k_outprojmfma(const _Float16* __restrict__ fusedH,
                                                     const _Float16* __restrict__ opH,
                                                     float* __restrict__ out) {
  int wid = threadIdx.x >> 6, lane = threadIdx.x & 63;
  int r = lane & 15, g = lane >> 4;
  int m0 = blockIdx.x * 64;
  int n0 = blockIdx.y * 256 + wid * 64;
  int b  = blockIdx.z;
  f4 acc[4][4];
#pragma unroll
  for (int mi = 0; mi < 4; ++mi)
#pragma unroll
    for (int ni = 0; ni < 4; ++ni) acc[mi][ni] = (f4){0.f, 0.f, 0.f, 0.f};
  for (int kk = 0; kk < 512; kk += 32) {
    half8 av[4], bv[4];
#pragma unroll
    for (int mi = 0; mi < 4; ++mi)
      av[mi] = *(const half8*)(opH + (size_t)(m0 + mi * 16 + r) * 512 + kk + g * 8);
#pragma unroll
    for (int ni = 0; ni < 4; ++ni)
      bv[ni] = *(const half8*)(fusedH + ((size_t)(b * 1024) + n0 + ni * 16 + r) * 512 + kk + g * 8);
#pragma unroll
    for (int mi = 0; mi < 4; ++mi)
#pragma unroll
      for (int ni = 0; ni < 4; ++ni)
        acc[mi][ni] = __builtin_amdgcn_mfma_f32_16x16x32_f16(av[mi], bv[ni], acc[mi][ni], 0, 0, 0);
  }
#pragma unroll
  for (int mi = 0; mi < 4; ++mi)
#pragma unroll
    for (int ni = 0; ni < 4; ++ni) {
      int pix = n0 + ni * 16 + r;
#pragma unroll
      for (int j = 0; j < 4; ++j) {
        int co = m0 + mi * 16 + g * 4 + j;
        out[((size_t)(b * 256) + co) * 1024 + pix] = geluf(acc[mi][ni][j]);
      }
    }
}

extern "C" void kernel_launch(void* const* d_in, const int* in_sizes, int n_in,
                              void* d_out, int out_size, void* d_ws, size_t ws_size,
                              hipStream_t stream) {
  const float* x    = (const float*)d_in[0];
  const float* inw  = (const float*)d_in[1];
  const float* opw  = (const float*)d_in[2];
  const float* cxw  = (const float*)d_in[3];
  const float* cxb  = (const float*)d_in[4];
  const float* czw  = (const float*)d_in[5];
  const float* czb  = (const float*)d_in[6];
  const float* xpw  = (const float*)d_in[7];
  const float* dtw  = (const float*)d_in[8];
  const float* dtb  = (const float*)d_in[9];
  const float* alog = (const float*)d_in[10];
  const float* ds   = (const float*)d_in[11];
  const float* saw1 = (const float*)d_in[12];
  const float* sab1 = (const float*)d_in[13];
  const float* saw2 = (const float*)d_in[14];
  const float* sab2 = (const float*)d_in[15];
  const float* caw1 = (const float*)d_in[16];
  const float* caw2 = (const float*)d_in[17];
  const float* gw   = (const float*)d_in[18];
  const float* gb   = (const float*)d_in[19];

  float* ws = (float*)d_ws;
  float* xz   = ws + 0;          //  4,194,304  [alias: aprodg -> Cpart -> catO fp16]
  float* xseq = ws + 4194304;    //  8,388,608  [alias: Ytg fp16]
  float* xdT  = ws + 12582912;   //  1,572,864  (k-major xdbl tiles)
  float* Y    = ws + 14155776;   // 16,777,216  rotated layout; carries embedded; later fusedH
  float* swb  = ws + 31981568;   //     32,768
  float* cavg = ws + 32014336;   //     16,384
  float* cwb  = ws + 32030720;   //         32
  float* inWT = ws + 32030752;   //    131,072
  float* opHF = ws + 32161824;   //    131,072 (opH fp16)
  float* gwHF = ws + 32292896;   //    524,288 (gwH fp16)
  float* WhgF = ws + 32817184;   //  1,179,648 (Whg fp16)
  float* aprodg = xz;            //  4,194,304 (32br x 32ch x 256d x 16n)
  float* Cpart  = xz;
  _Float16* Ytg    = (_Float16*)xseq;
  _Float16* catO   = (_Float16*)xz;      // after saconv2f consumed Cpart
  _Float16* fusedH = (_Float16*)Y;       // after cavg/ytr done with Y
  _Float16* Whg = (_Float16*)WhgF;
  _Float16* gwH = (_Float16*)gwHF;
  _Float16* opH = (_Float16*)opHF;

  k_prep<<<3072, 256, 0, stream>>>(inw, gw, opw, inWT, gwH, opH);
  k_wprep<<<9216, 256, 0, stream>>>(saw1, Whg);
  k_inproj<<<dim3(128, 8), 512, 0, stream>>>(x, inWT, xz);
  k_convx<<<dim3(4, 1024, 8), 256, 0, stream>>>(xz, cxw, cxb, xseq);
  k_convz<<<dim3(4, 1024, 8), 256, 0, stream>>>(xz, czw, czb, Y);
  k_xdblT<<<dim3(32, 32), 256, 0, stream>>>(xseq, xpw, xdT);
  k_scanA<<<dim3(32, 32), 256, 0, stream>>>(xseq, xdT, dtw, dtb, alog, aprodg, Y);
  k_scanB<<<512, 256, 0, stream>>>(aprodg, Y);
  k_scanC<<<dim3(32, 32), 256, 0, stream>>>(xseq, xdT, dtw, dtb, alog, ds, Y);
  k_ytr<<<dim3(8, 64, 8), 256, 0, stream>>>(Y, Ytg);
  k_samfma<<<dim3(64, 2, 4), 128, 0, stream>>>(Ytg, Whg, Cpart);
  k_saconv2f<<<dim3(4, 8), 256, 0, stream>>>(Cpart, sab1, saw2, sab2, swb);
  k_cavg<<<64, 256, 0, stream>>>(Y, cavg);
  k_cw<<<8, 64, 0, stream>>>(cavg, caw1, caw2, cwb);
  k_catH<<<dim3(16, 8, 8), 256, 0, stream>>>(Ytg, swb, cwb, catO);
  k_gatemfma<<<dim3(8, 4, 8), 256, 0, stream>>>(catO, gwH, gb, fusedH);
  k_outprojmfma<<<dim3(4, 4, 8), 256, 0, stream>>>(fusedH, opH, (float*)d_out);
}